// Round 6
// baseline (506.086 us; speedup 1.0000x reference)
//
#include <hip/hip_runtime.h>
#include <stdint.h>

// ResBlock: GraphConv(64->128) -> BN -> ReLU -> GraphConv(128->128) -> BN
//           + (x @ Wlin^T + blin) residual -> ReLU.
// Runtime dtype probe (bf16 vs f32).
// R14: ABLATION ROUND. gemm1 has sat at 60-75us (vs ~12us roofline) across
// three structures with all pipes <11% busy; occupancy doubling (R13) made
// it WORSE. Reverting gemm1 to best-known R10 form (59.8us) and appending
// probe kernels AFTER k_final (scratch-only writes, correctness preserved):
//   P0 k_probe<0>: gemm1 clone (control)
//   P2 k_probe<2>: no y1 stores (stats keep MFMA live)
//   P3 k_probe<3>: no MFMA (asm sinks keep ds_reads live)
//   P4 k_probe4  : direct-global MFMA feed (no LDS, no barriers)
// Each probe = one rocprof dispatch row -> phase decomposition of the 60us.
// Kept: R11 4-deep agg batches + PSH=8; R9/R10 persistent gemms, register
// BN stats, line-padded stat atomics, reg-prefetch, y0p materialization.

#define CIN 64
#define COUT 128
#define BN_EPS 1e-5f
#define CURPAD 32              // ints: one 128B line per cursor
#define PCPAD 32               // ints: one 128B line per pcount entry
#define SPAD 32                // floats: one 128B line per stats channel
#define PSH 8                  // partition = dst >> PSH  (256 nodes)
#define PNODES (1 << PSH)
#define MAXP 512               // supports N <= 131072

typedef unsigned short u16;
typedef short short8 __attribute__((ext_vector_type(8)));
typedef float f32x4 __attribute__((ext_vector_type(4)));

__device__ __forceinline__ float bf2f(u16 u) {
    union { unsigned int i; float f; } v; v.i = ((unsigned int)u) << 16; return v.f;
}
__device__ __forceinline__ u16 f2bf(float f) {
    union { float f; unsigned int i; } v; v.f = f;
    unsigned int r = v.i + 0x7fffu + ((v.i >> 16) & 1u);  // RNE; finite inputs
    return (u16)(r >> 16);
}
__device__ __forceinline__ float lo16(unsigned int w) { return bf2f((u16)(w & 0xffffu)); }
__device__ __forceinline__ float hi16(unsigned int w) { return bf2f((u16)(w >> 16)); }

template<bool BF> __device__ __forceinline__ float ldf(const void* p, long i) {
    if (BF) return bf2f(((const u16*)p)[i]);
    return ((const float*)p)[i];
}
template<bool BF> __device__ __forceinline__ short8 ld8(const void* p, long i) {
    if (BF) return *(const short8*)((const u16*)p + i);
    const float* f = (const float*)p + i;
    short8 r;
#pragma unroll
    for (int j = 0; j < 8; ++j) r[j] = (short)f2bf(f[j]);
    return r;
}

// ---------------- dtype detection ----------------
__global__ void k_detect(const unsigned int* __restrict__ x, int* __restrict__ flag) {
    int lane = threadIdx.x;  // 64
    int cnt = 0;
#pragma unroll
    for (int i = 0; i < 8; ++i) {
        unsigned int w = x[lane * 8 + i];
        unsigned int e0 = (w >> 7) & 0xFFu, e1 = (w >> 23) & 0xFFu;
        cnt += (e0 >= 0x60u && e0 <= 0x8Eu);
        cnt += (e1 >= 0x60u && e1 <= 0x8Eu);
    }
    for (int o = 32; o; o >>= 1) cnt += __shfl_down(cnt, o);
    if (lane == 0) *flag = (cnt > 850) ? 1 : 0;   // 1 => bf16
}

// ---------------- partition build (partition = dst >> PSH) ----------------
__global__ __launch_bounds__(256) void k_phist(const int* __restrict__ dst,
                                               int* __restrict__ pcount, int E, int np) {
    __shared__ int h[MAXP];
    for (int i = threadIdx.x; i < np; i += 256) h[i] = 0;
    __syncthreads();
    int stride = gridDim.x * 256;
    for (int e = blockIdx.x * 256 + threadIdx.x; e < E; e += stride)
        atomicAdd(&h[dst[e] >> PSH], 1);
    __syncthreads();
    for (int i = threadIdx.x; i < np; i += 256)
        if (h[i]) atomicAdd(&pcount[i * PCPAD], h[i]);
}

__global__ void k_pscan(const int* __restrict__ pcount, int* __restrict__ pstart,
                        int* __restrict__ pcursor, int np, int E) {
    __shared__ int s[MAXP];
    int t = threadIdx.x;  // MAXP threads
    int v = (t < np) ? pcount[t * PCPAD] : 0;
    s[t] = v; __syncthreads();
    for (int o = 1; o < MAXP; o <<= 1) {
        int u = (t >= o) ? s[t - o] : 0;
        __syncthreads(); s[t] += u; __syncthreads();
    }
    if (t < np) {
        int ex = s[t] - v;
        pstart[t] = ex;
        pcursor[t * CURPAD] = ex;
    }
    if (t == 0) pstart[np] = E;
}

// One 4096-edge tile per block. rec = (dst & (PNODES-1)) << 20 | src
__global__ __launch_bounds__(256) void k_pfill(const int* __restrict__ src,
        const int* __restrict__ dst, int* __restrict__ pcursor,
        unsigned int* __restrict__ barr, int E, int np) {
    __shared__ int cnt[MAXP], gb[MAXP], loc[MAXP];
    int tid = threadIdx.x;
    int base = blockIdx.x * 4096;
    for (int i = tid; i < np; i += 256) { cnt[i] = 0; loc[i] = 0; }
    __syncthreads();
    int pk[16]; unsigned int rec[16];
#pragma unroll
    for (int k = 0; k < 16; ++k) {
        int e = base + k * 256 + tid;
        if (e < E) {
            int d = dst[e];
            pk[k] = d >> PSH;
            rec[k] = ((unsigned int)(d & (PNODES - 1)) << 20) | (unsigned int)src[e];
            atomicAdd(&cnt[pk[k]], 1);
        } else pk[k] = -1;
    }
    __syncthreads();
    for (int i = tid; i < np; i += 256)
        if (cnt[i]) gb[i] = atomicAdd(&pcursor[i * CURPAD], cnt[i]);
    __syncthreads();
#pragma unroll
    for (int k = 0; k < 16; ++k) {
        if (pk[k] >= 0) {
            int off = atomicAdd(&loc[pk[k]], 1);
            barr[gb[pk[k]] + off] = rec[k];
        }
    }
}

// Block per partition (PNODES=256): LDS counting sort -> csr + row_start.
__global__ __launch_bounds__(256) void k_psort(const unsigned int* __restrict__ barr,
        const int* __restrict__ pstart, int* __restrict__ csr,
        int* __restrict__ row_start, int n, int np, int E) {
    __shared__ int hist[PNODES], curs[PNODES], tsum[256];
    int tid = threadIdx.x;
    int p = blockIdx.x;
    int e0 = pstart[p], e1 = pstart[p + 1];
    int node0 = p << PSH;
    hist[tid] = 0;
    __syncthreads();
    for (int t = e0 + tid; t < e1; t += 256)
        atomicAdd(&hist[barr[t] >> 20], 1);
    __syncthreads();
    int v = hist[tid];
    tsum[tid] = v; __syncthreads();
    for (int o = 1; o < 256; o <<= 1) {
        int u = (tid >= o) ? tsum[tid - o] : 0;
        __syncthreads(); tsum[tid] += u; __syncthreads();
    }
    int ex = tsum[tid] - v;
    curs[tid] = ex;
    int nd = node0 + tid;
    if (nd < n) row_start[nd] = e0 + ex;
    if (p == np - 1 && tid == 0) row_start[n] = E;
    __syncthreads();
    for (int t = e0 + tid; t < e1; t += 256) {
        unsigned int rec = barr[t];
        int pos = atomicAdd(&curs[rec >> 20], 1);
        csr[e0 + pos] = (int)(rec & 0xFFFFF);
    }
}

// ------------- aggregation 0 (pull, wave/node, 4-deep slot gathers) -------
template<bool BF>
__device__ __forceinline__ void agg0_impl(const void* x, const int* rs, const int* csr,
                                          u16* agg, int n) {
    int i = blockIdx.x * 4 + (threadIdx.x >> 6);
    if (i >= n) return;
    int lane = threadIdx.x & 63;
    int slot = lane >> 4, cp = lane & 15;   // 4 slots x 16 lanes
    int b = rs[i], e = rs[i + 1];
    if (BF) {
        const unsigned int* x32 = (const unsigned int*)x;
        float acc[4] = {0.f, 0.f, 0.f, 0.f};
        int t = b + slot;
        for (; t + 12 < e; t += 16) {
            int j0 = csr[t], j1 = csr[t + 4], j2 = csr[t + 8], j3 = csr[t + 12];
            uint2 w0 = *((const uint2*)(x32 + (long)j0 * 32) + cp);
            uint2 w1 = *((const uint2*)(x32 + (long)j1 * 32) + cp);
            uint2 w2 = *((const uint2*)(x32 + (long)j2 * 32) + cp);
            uint2 w3 = *((const uint2*)(x32 + (long)j3 * 32) + cp);
            acc[0] += lo16(w0.x) + lo16(w1.x); acc[1] += hi16(w0.x) + hi16(w1.x);
            acc[2] += lo16(w0.y) + lo16(w1.y); acc[3] += hi16(w0.y) + hi16(w1.y);
            acc[0] += lo16(w2.x) + lo16(w3.x); acc[1] += hi16(w2.x) + hi16(w3.x);
            acc[2] += lo16(w2.y) + lo16(w3.y); acc[3] += hi16(w2.y) + hi16(w3.y);
        }
        for (; t < e; t += 4) {
            int j0 = csr[t];
            uint2 w0 = *((const uint2*)(x32 + (long)j0 * 32) + cp);
            acc[0] += lo16(w0.x); acc[1] += hi16(w0.x);
            acc[2] += lo16(w0.y); acc[3] += hi16(w0.y);
        }
#pragma unroll
        for (int k = 0; k < 4; ++k) {
            acc[k] += __shfl_xor(acc[k], 16);
            acc[k] += __shfl_xor(acc[k], 32);
        }
        if (slot == 0) {
            uint2 o;
            o.x = (unsigned int)f2bf(acc[0]) | ((unsigned int)f2bf(acc[1]) << 16);
            o.y = (unsigned int)f2bf(acc[2]) | ((unsigned int)f2bf(acc[3]) << 16);
            *((uint2*)((unsigned int*)agg + (long)i * 32) + cp) = o;
        }
    } else {
        float acc[4] = {0.f, 0.f, 0.f, 0.f};
        int t = b + slot;
        for (; t + 12 < e; t += 16) {
            int j0 = csr[t], j1 = csr[t + 4], j2 = csr[t + 8], j3 = csr[t + 12];
            float4 w0 = *((const float4*)((const float*)x + (long)j0 * 64) + cp);
            float4 w1 = *((const float4*)((const float*)x + (long)j1 * 64) + cp);
            float4 w2 = *((const float4*)((const float*)x + (long)j2 * 64) + cp);
            float4 w3 = *((const float4*)((const float*)x + (long)j3 * 64) + cp);
            acc[0] += (w0.x + w1.x) + (w2.x + w3.x);
            acc[1] += (w0.y + w1.y) + (w2.y + w3.y);
            acc[2] += (w0.z + w1.z) + (w2.z + w3.z);
            acc[3] += (w0.w + w1.w) + (w2.w + w3.w);
        }
        for (; t < e; t += 4) {
            int j0 = csr[t];
            float4 w0 = *((const float4*)((const float*)x + (long)j0 * 64) + cp);
            acc[0] += w0.x; acc[1] += w0.y; acc[2] += w0.z; acc[3] += w0.w;
        }
#pragma unroll
        for (int k = 0; k < 4; ++k) {
            acc[k] += __shfl_xor(acc[k], 16);
            acc[k] += __shfl_xor(acc[k], 32);
        }
        if (slot == 0) {
            uint2 o;
            o.x = (unsigned int)f2bf(acc[0]) | ((unsigned int)f2bf(acc[1]) << 16);
            o.y = (unsigned int)f2bf(acc[2]) | ((unsigned int)f2bf(acc[3]) << 16);
            *((uint2*)((unsigned int*)agg + (long)i * 32) + cp) = o;
        }
    }
}

__global__ __launch_bounds__(256) void k_agg0(const int* __restrict__ flag,
        const void* x, const int* __restrict__ rs, const int* __restrict__ csr,
        u16* __restrict__ agg, int n) {
    if (*flag) agg0_impl<true >(x, rs, csr, agg, n);
    else       agg0_impl<false>(x, rs, csr, agg, n);
}

// ---- y0p = relu(bn0(y0)) materialized IN-PLACE (bf16), streaming --------
__global__ __launch_bounds__(256) void k_y0p(unsigned int* __restrict__ y0,
        const float* __restrict__ sc, const float* __restrict__ sh, long nq) {
    long idx = (long)blockIdx.x * 256 + threadIdx.x;
    int colq = threadIdx.x & 15;
    float s8[8], h8[8];
#pragma unroll
    for (int j = 0; j < 8; ++j) { s8[j] = sc[colq * 8 + j]; h8[j] = sh[colq * 8 + j]; }
    long stride = (long)gridDim.x * 256;
    uint4* p = (uint4*)y0;
    for (; idx < nq; idx += stride) {
        uint4 w = p[idx];
        unsigned int r[4] = {w.x, w.y, w.z, w.w};
        uint4 o;
        unsigned int* po = (unsigned int*)&o;
#pragma unroll
        for (int d = 0; d < 4; ++d) {
            float a = fmaxf(lo16(r[d]) * s8[2 * d]     + h8[2 * d],     0.f);
            float b = fmaxf(hi16(r[d]) * s8[2 * d + 1] + h8[2 * d + 1], 0.f);
            po[d] = (unsigned int)f2bf(a) | ((unsigned int)f2bf(b) << 16);
        }
        p[idx] = o;
    }
}

// ------------- aggregation 1 (pure bf16 gather-sum, 4-deep batches) -------
__global__ __launch_bounds__(256) void k_agg1(const u16* __restrict__ y0p,
        const int* __restrict__ rs, const int* __restrict__ csr,
        u16* __restrict__ agg, int n) {
    int i = blockIdx.x * 4 + (threadIdx.x >> 6);
    if (i >= n) return;
    int lane = threadIdx.x & 63;
    int slot = lane >> 4, cp = lane & 15;   // y0p row = 256B = 16 x uint4
    const unsigned int* y32 = (const unsigned int*)y0p;
    int b = rs[i], e = rs[i + 1];
    float acc[8] = {0.f, 0.f, 0.f, 0.f, 0.f, 0.f, 0.f, 0.f};
    int t = b + slot;
    for (; t + 12 < e; t += 16) {
        int j0 = csr[t], j1 = csr[t + 4], j2 = csr[t + 8], j3 = csr[t + 12];
        uint4 w0 = *((const uint4*)(y32 + (long)j0 * 64) + cp);
        uint4 w1 = *((const uint4*)(y32 + (long)j1 * 64) + cp);
        uint4 w2 = *((const uint4*)(y32 + (long)j2 * 64) + cp);
        uint4 w3 = *((const uint4*)(y32 + (long)j3 * 64) + cp);
        acc[0] += lo16(w0.x) + lo16(w1.x); acc[1] += hi16(w0.x) + hi16(w1.x);
        acc[2] += lo16(w0.y) + lo16(w1.y); acc[3] += hi16(w0.y) + hi16(w1.y);
        acc[4] += lo16(w0.z) + lo16(w1.z); acc[5] += hi16(w0.z) + hi16(w1.z);
        acc[6] += lo16(w0.w) + lo16(w1.w); acc[7] += hi16(w0.w) + hi16(w1.w);
        acc[0] += lo16(w2.x) + lo16(w3.x); acc[1] += hi16(w2.x) + hi16(w3.x);
        acc[2] += lo16(w2.y) + lo16(w3.y); acc[3] += hi16(w2.y) + hi16(w3.y);
        acc[4] += lo16(w2.z) + lo16(w3.z); acc[5] += hi16(w2.z) + hi16(w3.z);
        acc[6] += lo16(w2.w) + lo16(w3.w); acc[7] += hi16(w2.w) + hi16(w3.w);
    }
    for (; t < e; t += 4) {
        int j0 = csr[t];
        uint4 w0 = *((const uint4*)(y32 + (long)j0 * 64) + cp);
        acc[0] += lo16(w0.x); acc[1] += hi16(w0.x);
        acc[2] += lo16(w0.y); acc[3] += hi16(w0.y);
        acc[4] += lo16(w0.z); acc[5] += hi16(w0.z);
        acc[6] += lo16(w0.w); acc[7] += hi16(w0.w);
    }
#pragma unroll
    for (int k = 0; k < 8; ++k) {
        acc[k] += __shfl_xor(acc[k], 16);
        acc[k] += __shfl_xor(acc[k], 32);
    }
    if (slot == 0) {
        uint4 o;
        o.x = (unsigned int)f2bf(acc[0]) | ((unsigned int)f2bf(acc[1]) << 16);
        o.y = (unsigned int)f2bf(acc[2]) | ((unsigned int)f2bf(acc[3]) << 16);
        o.z = (unsigned int)f2bf(acc[4]) | ((unsigned int)f2bf(acc[5]) << 16);
        o.w = (unsigned int)f2bf(acc[6]) | ((unsigned int)f2bf(acc[7]) << 16);
        *((uint4*)((unsigned int*)agg + (long)i * 64) + cp) = o;
    }
}

// ---------------- GEMM0: y0 = [x|agg0] @ [Wr0;Wn0]^T, fused stats ----------
template<bool BF>
__device__ __forceinline__ void gemm0_impl(const void* x, const u16* agg,
                                           const void* Wr, const void* Wn,
                                           u16* y0, float* sumP, float* sqP,
                                           int n, int nch, u16* lds) {
    const int ST = 130;
    int tid = threadIdx.x;
    int wave = tid >> 6, lane = tid & 63, lr = lane & 15, q = lane >> 4;

    short8 wf[2][4];
#pragma unroll
    for (int i = 0; i < 2; ++i) {
        int c = (2 * wave + i) * 16 + lr;
#pragma unroll
        for (int ks = 0; ks < 4; ++ks) {
            const void* W = (ks < 2) ? Wr : Wn;
            wf[i][ks] = ld8<BF>(W, (long)c * CIN + (ks & 1) * 32 + q * 8);
        }
    }

    const int rowb = tid >> 3, wb = tid & 7;
    const int rowf = tid >> 4, wfc = tid & 15;
    short8 rbx[2]; float4 rfx[4]; short8 rag[2];

    auto regload = [&](long chunk0) {
        if (BF) {
#pragma unroll
            for (int i = 0; i < 2; ++i) {
                long rg = chunk0 + rowb + i * 32; if (rg > n - 1) rg = n - 1;
                rbx[i] = *(const short8*)((const u16*)x + rg * CIN + wb * 8);
            }
        } else {
#pragma unroll
            for (int i = 0; i < 4; ++i) {
                long rg = chunk0 + rowf + i * 16; if (rg > n - 1) rg = n - 1;
                rfx[i] = *(const float4*)((const float*)x + rg * CIN + wfc * 4);
            }
        }
#pragma unroll
        for (int i = 0; i < 2; ++i) {
            long rg = chunk0 + rowb + i * 32; if (rg > n - 1) rg = n - 1;
            rag[i] = *(const short8*)(agg + rg * CIN + wb * 8);
        }
    };

    float st[2] = {0.f, 0.f}, sq[2] = {0.f, 0.f};
    int ch = blockIdx.x;
    if (ch < nch) regload((long)ch * 64);
    for (; ch < nch; ch += gridDim.x) {
        long chunk0 = (long)ch * 64;
        __syncthreads();
        if (BF) {
#pragma unroll
            for (int i = 0; i < 2; ++i)
                *(short8*)(lds + (rowb + i * 32) * ST + wb * 8) = rbx[i];
        } else {
#pragma unroll
            for (int i = 0; i < 4; ++i) {
                u16* d = lds + (rowf + i * 16) * ST + wfc * 4;
                d[0] = f2bf(rfx[i].x); d[1] = f2bf(rfx[i].y);
                d[2] = f2bf(rfx[i].z); d[3] = f2bf(rfx[i].w);
            }
        }
#pragma unroll
        for (int i = 0; i < 2; ++i)
            *(short8*)(lds + (rowb + i * 32) * ST + 64 + wb * 8) = rag[i];
        __syncthreads();
        long nxt = (long)ch + gridDim.x;
        if (nxt < nch) regload(nxt * 64);

#pragma unroll
        for (int t = 0; t < 4; ++t) {
            short8 a[4];
#pragma unroll
            for (int ks = 0; ks < 4; ++ks)
                a[ks] = *(const short8*)(lds + (t * 16 + lr) * ST + ks * 32 + q * 8);
#pragma unroll
            for (int i = 0; i < 2; ++i) {
                f32x4 acc = {0.f, 0.f, 0.f, 0.f};
#pragma unroll
                for (int ks = 0; ks < 4; ++ks)
                    acc = __builtin_amdgcn_mfma_f32_16x16x32_bf16(a[ks], wf[i][ks], acc, 0, 0, 0);
                int c = (2 * wave + i) * 16 + lr;
#pragma unroll
                for (int r = 0; r < 4; ++r) {
                    long row = chunk0 + t * 16 + q * 4 + r;
                    if (row < n) {
                        y0[row * COUT + c] = f2bf(acc[r]);   // b0 cancels in BN
                        st[i] += acc[r]; sq[i] += acc[r] * acc[r];
                    }
                }
            }
        }
    }
#pragma unroll
    for (int i = 0; i < 2; ++i) {
        st[i] += __shfl_xor(st[i], 16); st[i] += __shfl_xor(st[i], 32);
        sq[i] += __shfl_xor(sq[i], 16); sq[i] += __shfl_xor(sq[i], 32);
    }
    if (q == 0) {
#pragma unroll
        for (int i = 0; i < 2; ++i) {
            int c = (2 * wave + i) * 16 + lr;
            atomicAdd(&sumP[c * SPAD], st[i]);
            atomicAdd(&sqP[c * SPAD], sq[i]);
        }
    }
}

__global__ __launch_bounds__(256) void k_gemm0(const int* __restrict__ flag,
        const void* x, const u16* __restrict__ agg, const void* Wr, const void* Wn,
        u16* __restrict__ y0, float* __restrict__ sumP, float* __restrict__ sqP,
        int n, int nch) {
    __shared__ u16 lds[64 * 130];
    if (*flag) gemm0_impl<true >(x, agg, Wr, Wn, y0, sumP, sqP, n, nch, lds);
    else       gemm0_impl<false>(x, agg, Wr, Wn, y0, sumP, sqP, n, nch, lds);
}

// ---------------- GEMM1 (R10 form): y1 = [y0p|agg1] @ [Wr1;Wn1]^T ---------
template<bool BF>
__device__ __forceinline__ void gemm1_impl(const u16* y0p, const u16* agg,
                                           const void* Wr, const void* Wn,
                                           u16* y1, float* sumP, float* sqP,
                                           int n, int nch, u16* lds) {
    const int ST = 258;
    int tid = threadIdx.x;
    int wave = tid >> 6, lane = tid & 63, lr = lane & 15, q = lane >> 4;

    short8 wf[2][8];
#pragma unroll
    for (int i = 0; i < 2; ++i) {
        int c = (2 * wave + i) * 16 + lr;
#pragma unroll
        for (int ks = 0; ks < 8; ++ks) {
            const void* W = (ks < 4) ? Wr : Wn;
            wf[i][ks] = ld8<BF>(W, (long)c * COUT + (ks & 3) * 32 + q * 8);
        }
    }

    const int rowy = tid >> 4, wy = tid & 15;   // 128-wide rows: 4/thread
    short8 ry[4], rag[4];
    auto regload = [&](long chunk0) {
#pragma unroll
        for (int i = 0; i < 4; ++i) {
            long rg = chunk0 + rowy + i * 16; if (rg > n - 1) rg = n - 1;
            ry[i]  = *(const short8*)(y0p + rg * COUT + wy * 8);
            rag[i] = *(const short8*)(agg + rg * COUT + wy * 8);
        }
    };

    float st[2] = {0.f, 0.f}, sq[2] = {0.f, 0.f};
    int ch = blockIdx.x;
    if (ch < nch) regload((long)ch * 64);
    for (; ch < nch; ch += gridDim.x) {
        long chunk0 = (long)ch * 64;
        __syncthreads();
#pragma unroll
        for (int i = 0; i < 4; ++i) {
            *(short8*)(lds + (rowy + i * 16) * ST + wy * 8) = ry[i];
            *(short8*)(lds + (rowy + i * 16) * ST + 128 + wy * 8) = rag[i];
        }
        __syncthreads();
        long nxt = (long)ch + gridDim.x;
        if (nxt < nch) regload(nxt * 64);

#pragma unroll
        for (int t = 0; t < 4; ++t) {
            short8 a[8];
#pragma unroll
            for (int ks = 0; ks < 8; ++ks)
                a[ks] = *(const short8*)(lds + (t * 16 + lr) * ST + ks * 32 + q * 8);
#pragma unroll
            for (int i = 0; i < 2; ++i) {
                f32x4 acc = {0.f, 0.f, 0.f, 0.f};
#pragma unroll
                for (int ks = 0; ks < 8; ++ks)
                    acc = __builtin_amdgcn_mfma_f32_16x16x32_bf16(a[ks], wf[i][ks], acc, 0, 0, 0);
                int c = (2 * wave + i) * 16 + lr;
#pragma unroll
                for (int r = 0; r < 4; ++r) {
                    long row = chunk0 + t * 16 + q * 4 + r;
                    if (row < n) {
                        y1[row * COUT + c] = f2bf(acc[r]);   // b1 cancels in BN
                        st[i] += acc[r]; sq[i] += acc[r] * acc[r];
                    }
                }
            }
        }
    }
#pragma unroll
    for (int i = 0; i < 2; ++i) {
        st[i] += __shfl_xor(st[i], 16); st[i] += __shfl_xor(st[i], 32);
        sq[i] += __shfl_xor(sq[i], 16); sq[i] += __shfl_xor(sq[i], 32);
    }
    if (q == 0) {
#pragma unroll
        for (int i = 0; i < 2; ++i) {
            int c = (2 * wave + i) * 16 + lr;
            atomicAdd(&sumP[c * SPAD], st[i]);
            atomicAdd(&sqP[c * SPAD], sq[i]);
        }
    }
}

__global__ __launch_bounds__(256) void k_gemm1(const int* __restrict__ flag,
        const u16* __restrict__ y0p, const u16* __restrict__ agg,
        const void* Wr, const void* Wn,
        u16* y1_bf /*=d_out*/, u16* y1_ws,
        float* __restrict__ sumP, float* __restrict__ sqP, int n, int nch) {
    __shared__ u16 lds[64 * 258];
    u16* y1 = *flag ? y1_bf : y1_ws;
    if (*flag) gemm1_impl<true >(y0p, agg, Wr, Wn, y1, sumP, sqP, n, nch, lds);
    else       gemm1_impl<false>(y0p, agg, Wr, Wn, y1, sumP, sqP, n, nch, lds);
}

// ---------------- PROBES (scratch-only; launched after k_final) -----------
// MODE 0: full gemm1 clone (control)
// MODE 2: no y1 stores (stats keep MFMA live)
// MODE 3: no MFMA (asm sinks keep ds_reads live; stores zeros)
template<int MODE>
__global__ __launch_bounds__(256) void k_probe(const u16* __restrict__ y0p,
        const u16* __restrict__ agg, const void* Wr, const void* Wn,
        u16* __restrict__ y1, float* __restrict__ sumP, float* __restrict__ sqP,
        int n, int nch) {
    __shared__ u16 lds[64 * 258];
    const int ST = 258;
    int tid = threadIdx.x;
    int wave = tid >> 6, lane = tid & 63, lr = lane & 15, q = lane >> 4;

    short8 wf[2][8];
#pragma unroll
    for (int i = 0; i < 2; ++i) {
        int c = (2 * wave + i) * 16 + lr;
#pragma unroll
        for (int ks = 0; ks < 8; ++ks) {
            const void* W = (ks < 4) ? Wr : Wn;
            wf[i][ks] = ld8<true>(W, (long)c * COUT + (ks & 3) * 32 + q * 8);
        }
    }

    const int rowy = tid >> 4, wy = tid & 15;
    short8 ry[4], rag[4];
    auto regload = [&](long chunk0) {
#pragma unroll
        for (int i = 0; i < 4; ++i) {
            long rg = chunk0 + rowy + i * 16; if (rg > n - 1) rg = n - 1;
            ry[i]  = *(const short8*)(y0p + rg * COUT + wy * 8);
            rag[i] = *(const short8*)(agg + rg * COUT + wy * 8);
        }
    };

    float st[2] = {0.f, 0.f}, sq[2] = {0.f, 0.f};
    int ch = blockIdx.x;
    if (ch < nch) regload((long)ch * 64);
    for (; ch < nch; ch += gridDim.x) {
        long chunk0 = (long)ch * 64;
        __syncthreads();
#pragma unroll
        for (int i = 0; i < 4; ++i) {
            *(short8*)(lds + (rowy + i * 16) * ST + wy * 8) = ry[i];
            *(short8*)(lds + (rowy + i * 16) * ST + 128 + wy * 8) = rag[i];
        }
        __syncthreads();
        long nxt = (long)ch + gridDim.x;
        if (nxt < nch) regload(nxt * 64);

#pragma unroll
        for (int t = 0; t < 4; ++t) {
            short8 a[8];
#pragma unroll
            for (int ks = 0; ks < 8; ++ks)
                a[ks] = *(const short8*)(lds + (t * 16 + lr) * ST + ks * 32 + q * 8);
            if (MODE == 3) {
#pragma unroll
                for (int ks = 0; ks < 8; ++ks) {
                    const unsigned int* ap = (const unsigned int*)&a[ks];
                    asm volatile("" :: "v"(ap[0]), "v"(ap[1]), "v"(ap[2]), "v"(ap[3]));
                }
            }
#pragma unroll
            for (int i = 0; i < 2; ++i) {
                f32x4 acc = {0.f, 0.f, 0.f, 0.f};
                if (MODE != 3) {
#pragma unroll
                    for (int ks = 0; ks < 8; ++ks)
                        acc = __builtin_amdgcn_mfma_f32_16x16x32_bf16(a[ks], wf[i][ks], acc, 0, 0, 0);
                }
                int c = (2 * wave + i) * 16 + lr;
#pragma unroll
                for (int r = 0; r < 4; ++r) {
                    long row = chunk0 + t * 16 + q * 4 + r;
                    if (row < n) {
                        if (MODE != 2) y1[row * COUT + c] = f2bf(acc[r]);
                        st[i] += acc[r]; sq[i] += acc[r] * acc[r];
                    }
                }
            }
        }
    }
#pragma unroll
    for (int i = 0; i < 2; ++i) {
        st[i] += __shfl_xor(st[i], 16); st[i] += __shfl_xor(st[i], 32);
        sq[i] += __shfl_xor(sq[i], 16); sq[i] += __shfl_xor(sq[i], 32);
    }
    if (q == 0) {
#pragma unroll
        for (int i = 0; i < 2; ++i) {
            int c = (2 * wave + i) * 16 + lr;
            atomicAdd(&sumP[c * SPAD], st[i]);
            atomicAdd(&sqP[c * SPAD], sq[i]);
        }
    }
}

// P4: direct-global MFMA feed -- no LDS, no barriers, no staging.
__global__ __launch_bounds__(256) void k_probe4(const u16* __restrict__ y0p,
        const u16* __restrict__ agg, const void* Wr, const void* Wn,
        u16* __restrict__ y1, float* __restrict__ sumP, float* __restrict__ sqP,
        int n, int nch) {
    int tid = threadIdx.x;
    int wave = tid >> 6, lane = tid & 63, lr = lane & 15, q = lane >> 4;

    short8 wf[2][8];
#pragma unroll
    for (int i = 0; i < 2; ++i) {
        int c = (2 * wave + i) * 16 + lr;
#pragma unroll
        for (int ks = 0; ks < 8; ++ks) {
            const void* W = (ks < 4) ? Wr : Wn;
            wf[i][ks] = ld8<true>(W, (long)c * COUT + (ks & 3) * 32 + q * 8);
        }
    }

    float st[2] = {0.f, 0.f}, sq[2] = {0.f, 0.f};
    for (int ch = blockIdx.x; ch < nch; ch += gridDim.x) {
        long chunk0 = (long)ch * 64;
#pragma unroll
        for (int t = 0; t < 4; ++t) {
            long rg = chunk0 + t * 16 + lr; if (rg > n - 1) rg = n - 1;
            short8 a[8];
#pragma unroll
            for (int ks = 0; ks < 4; ++ks)
                a[ks] = *(const short8*)(y0p + rg * COUT + ks * 32 + q * 8);
#pragma unroll
            for (int ks = 0; ks < 4; ++ks)
                a[4 + ks] = *(const short8*)(agg + rg * COUT + ks * 32 + q * 8);
#pragma unroll
            for (int i = 0; i < 2; ++i) {
                f32x4 acc = {0.f, 0.f, 0.f, 0.f};
#pragma unroll
                for (int ks = 0; ks < 8; ++ks)
                    acc = __builtin_amdgcn_mfma_f32_16x16x32_bf16(a[ks], wf[i][ks], acc, 0, 0, 0);
                int c = (2 * wave + i) * 16 + lr;
#pragma unroll
                for (int r = 0; r < 4; ++r) {
                    long row = chunk0 + t * 16 + q * 4 + r;
                    if (row < n) {
                        y1[row * COUT + c] = f2bf(acc[r]);
                        st[i] += acc[r]; sq[i] += acc[r] * acc[r];
                    }
                }
            }
        }
    }
#pragma unroll
    for (int i = 0; i < 2; ++i) {
        st[i] += __shfl_xor(st[i], 16); st[i] += __shfl_xor(st[i], 32);
        sq[i] += __shfl_xor(sq[i], 16); sq[i] += __shfl_xor(sq[i], 32);
    }
    if (q == 0) {
#pragma unroll
        for (int i = 0; i < 2; ++i) {
            int c = (2 * wave + i) * 16 + lr;
            atomicAdd(&sumP[c * SPAD], st[i]);
            atomicAdd(&sqP[c * SPAD], sq[i]);
        }
    }
}

// ---------------- BN finalize (reads line-padded stats) ----------------
__global__ void k_bnfin(const int* __restrict__ flag,
                        const float* __restrict__ sumP, const float* __restrict__ sqP,
                        const void* g, const void* be,
                        float* __restrict__ scale, float* __restrict__ shift, int n) {
    int c = threadIdx.x;
    bool bf = (*flag != 0);
    float inv = 1.f / (float)n;
    float mu = sumP[c * SPAD] * inv;
    float var = fmaxf(sqP[c * SPAD] * inv - mu * mu, 0.f);
    float gv = bf ? bf2f(((const u16*)g)[c]) : ((const float*)g)[c];
    float bv = bf ? bf2f(((const u16*)be)[c]) : ((const float*)be)[c];
    float sc = gv * rsqrtf(var + BN_EPS);
    scale[c] = sc;
    shift[c] = bv - mu * sc;
}

// ---------------- final: out = relu(bn1(y1) + x@Wlin^T + blin) ------------
template<bool BF>
__device__ __forceinline__ void final_impl(const void* x, const u16* y1,
                                           const void* Wlin, const void* blin,
                                           const float* sc, const float* sh,
                                           void* out, int n, int nch, u16* lds) {
    const int ST = 194;
    int tid = threadIdx.x;
    int wave = tid >> 6, lane = tid & 63, lr = lane & 15, q = lane >> 4;

    short8 wf[2][2];
    float blc[2], scc[2], shc[2];
#pragma unroll
    for (int i = 0; i < 2; ++i) {
        int c = (2 * wave + i) * 16 + lr;
#pragma unroll
        for (int ks = 0; ks < 2; ++ks)
            wf[i][ks] = ld8<BF>(Wlin, (long)c * CIN + ks * 32 + q * 8);
        blc[i] = ldf<BF>(blin, c);
        scc[i] = sc[c]; shc[i] = sh[c];
    }

    const int rowb = tid >> 3, wb = tid & 7;
    const int rowf = tid >> 4, wfc = tid & 15;
    const int rowy = tid >> 4, wy = tid & 15;
    short8 rbx[2]; float4 rfx[4]; short8 ry[4];

    auto regload = [&](long chunk0) {
        if (BF) {
#pragma unroll
            for (int i = 0; i < 2; ++i) {
                long rg = chunk0 + rowb + i * 32; if (rg > n - 1) rg = n - 1;
                rbx[i] = *(const short8*)((const u16*)x + rg * CIN + wb * 8);
            }
        } else {
#pragma unroll
            for (int i = 0; i < 4; ++i) {
                long rg = chunk0 + rowf + i * 16; if (rg > n - 1) rg = n - 1;
                rfx[i] = *(const float4*)((const float*)x + rg * CIN + wfc * 4);
            }
        }
#pragma unroll
        for (int i = 0; i < 4; ++i) {
            long rg = chunk0 + rowy + i * 16; if (rg > n - 1) rg = n - 1;
            ry[i] = *(const short8*)(y1 + rg * COUT + wy * 8);
        }
    };

    int ch = blockIdx.x;
    if (ch < nch) regload((long)ch * 64);
    for (; ch < nch; ch += gridDim.x) {
        long chunk0 = (long)ch * 64;
        __syncthreads();
        if (BF) {
#pragma unroll
            for (int i = 0; i < 2; ++i)
                *(short8*)(lds + (rowb + i * 32) * ST + wb * 8) = rbx[i];
        } else {
#pragma unroll
            for (int i = 0; i < 4; ++i) {
                u16* d = lds + (rowf + i * 16) * ST + wfc * 4;
                d[0] = f2bf(rfx[i].x); d[1] = f2bf(rfx[i].y);
                d[2] = f2bf(rfx[i].z); d[3] = f2bf(rfx[i].w);
            }
        }
#pragma unroll
        for (int i = 0; i < 4; ++i)
            *(short8*)(lds + (rowy + i * 16) * ST + 64 + wy * 8) = ry[i];
        __syncthreads();
        long nxt = (long)ch + gridDim.x;
        if (nxt < nch) regload(nxt * 64);

#pragma unroll
        for (int t = 0; t < 4; ++t) {
            short8 a[2];
#pragma unroll
            for (int ks = 0; ks < 2; ++ks)
                a[ks] = *(const short8*)(lds + (t * 16 + lr) * ST + ks * 32 + q * 8);
#pragma unroll
            for (int i = 0; i < 2; ++i) {
                f32x4 acc = {0.f, 0.f, 0.f, 0.f};
                acc = __builtin_amdgcn_mfma_f32_16x16x32_bf16(a[0], wf[i][0], acc, 0, 0, 0);
                acc = __builtin_amdgcn_mfma_f32_16x16x32_bf16(a[1], wf[i][1], acc, 0, 0, 0);
                int c = (2 * wave + i) * 16 + lr;
#pragma unroll
                for (int r = 0; r < 4; ++r) {
                    long row = chunk0 + t * 16 + q * 4 + r;
                    if (row < n) {
                        float yv = bf2f(lds[(t * 16 + q * 4 + r) * ST + 64 + c]);
                        float v = acc[r] + blc[i] + yv * scc[i] + shc[i];
                        v = fmaxf(v, 0.f);
                        if (BF) ((u16*)out)[row * COUT + c] = f2bf(v);
                        else    ((float*)out)[row * COUT + c] = v;
                    }
                }
            }
        }
    }
}

__global__ __launch_bounds__(256) void k_final(const int* __restrict__ flag,
        const void* x, const void* Wlin, const void* blin,
        const u16* y1_bf /*=d_out*/, const u16* y1_ws,
        const float* __restrict__ sc, const float* __restrict__ sh,
        void* out, int n, int nch) {
    __shared__ u16 lds[64 * 194];
    const u16* y1 = *flag ? y1_bf : y1_ws;
    if (*flag) final_impl<true >(x, y1, Wlin, blin, sc, sh, out, n, nch, lds);
    else       final_impl<false>(x, y1, Wlin, blin, sc, sh, out, n, nch, lds);
}

extern "C" void kernel_launch(void* const* d_in, const int* in_sizes, int n_in,
                              void* d_out, int out_size, void* d_ws, size_t ws_size,
                              hipStream_t stream) {
    (void)n_in; (void)out_size; (void)ws_size;
    const void* x    = d_in[0];
    const int*  ei   = (const int*)d_in[1];
    const void* Wr0  = d_in[2];
    const void* Wn0  = d_in[3];
    /* b0 dropped: BN-invariant */
    const void* g0   = d_in[5];
    const void* be0  = d_in[6];
    const void* Wr1  = d_in[7];
    const void* Wn1  = d_in[8];
    /* b1 dropped */
    const void* g1   = d_in[10];
    const void* be1  = d_in[11];
    const void* Wlin = d_in[12];
    const void* blin = d_in[13];

    const int N = in_sizes[0] / CIN;
    const int E = in_sizes[1] / 2;
    const int* src = ei;
    const int* dst = ei + E;
    const int NP = (N + PNODES - 1) >> PSH;

    // ---- workspace carve (256B aligned); f32-only region LAST ----
    char* base = (char*)d_ws;
    size_t off = 0;
    auto carve = [&](size_t bytes) -> void* {
        void* p = base + off;
        off = (off + bytes + 255) & ~(size_t)255;
        return p;
    };
    int*   flag      = (int*)carve(256);
    int*   pcount    = (int*)carve(MAXP * PCPAD * sizeof(int));
    int*   pstart    = (int*)carve((MAXP + 1) * sizeof(int));
    int*   pcursor   = (int*)carve(MAXP * CURPAD * sizeof(int));
    float* statsP    = (float*)carve(4 * 128 * SPAD * sizeof(float));
    float* pstats    = (float*)carve(2 * 128 * SPAD * sizeof(float)); // probe stats (never read)
    float* scsh      = (float*)carve(512 * sizeof(float));
    int*   row_start = (int*)carve((size_t)(N + 1) * sizeof(int));
    unsigned int* barr = (unsigned int*)carve((size_t)E * sizeof(int));
    int*   csr       = (int*)carve((size_t)E * sizeof(int));
    u16*   aggu      = (u16*)carve((size_t)N * COUT * sizeof(u16));
    u16*   y0        = (u16*)carve((size_t)N * COUT * sizeof(u16));
    u16*   y1_ws     = (u16*)carve((size_t)N * COUT * sizeof(u16));
    u16*   pscr      = (u16*)carve((size_t)N * COUT * sizeof(u16)); // probe scratch out

    float* sum0P = statsP;
    float* sq0P  = statsP + 128 * SPAD;
    float* sum1P = statsP + 256 * SPAD;
    float* sq1P  = statsP + 384 * SPAD;

    hipMemsetAsync(pcount, 0, MAXP * PCPAD * sizeof(int), stream);
    hipMemsetAsync(statsP, 0, 4 * 128 * SPAD * sizeof(float), stream);

    const int nwb = (N + 3) / 4;
    const int nch = (N + 63) / 64;
    const int ntl = (E + 4095) / 4096;
    const int G   = nch < 1024 ? nch : 1024;
    const long nq = (long)N * 16;
    int g2 = (int)((nq + 255) / 256); if (g2 > 2048) g2 = 2048;

    k_detect<<<1, 64, 0, stream>>>((const unsigned int*)x, flag);

    k_phist<<<256, 256, 0, stream>>>(dst, pcount, E, NP);
    k_pscan<<<1, MAXP, 0, stream>>>(pcount, pstart, pcursor, NP, E);
    k_pfill<<<ntl, 256, 0, stream>>>(src, dst, pcursor, barr, E, NP);
    k_psort<<<NP, 256, 0, stream>>>(barr, pstart, csr, row_start, N, NP, E);

    k_agg0 <<<nwb, 256, 0, stream>>>(flag, x, row_start, csr, aggu, N);
    k_gemm0<<<G, 256, 0, stream>>>(flag, x, aggu, Wr0, Wn0, y0,
                                   sum0P, sq0P, N, nch);
    k_bnfin<<<1, 128, 0, stream>>>(flag, sum0P, sq0P, g0, be0,
                                   scsh, scsh + 128, N);

    k_y0p<<<g2, 256, 0, stream>>>((unsigned int*)y0, scsh, scsh + 128, nq);

    k_agg1 <<<nwb, 256, 0, stream>>>(y0, row_start, csr, aggu, N);
    k_gemm1<<<G, 256, 0, stream>>>(flag, y0, aggu, Wr1, Wn1,
                                   (u16*)d_out, y1_ws, sum1P, sq1P, N, nch);
    k_bnfin<<<1, 128, 0, stream>>>(flag, sum1P, sq1P, g1, be1,
                                   scsh + 256, scsh + 384, N);

    k_final<<<G, 256, 0, stream>>>(flag, x, Wlin, blin,
                                   (const u16*)d_out, y1_ws,
                                   scsh + 256, scsh + 384, d_out, N, nch);

    // ---- ablation probes (scratch-only; after all real work) ----
    float* psum = pstats;
    float* psq  = pstats + 128 * SPAD;
    k_probe<0><<<G, 256, 0, stream>>>(y0, aggu, Wr1, Wn1, pscr, psum, psq, N, nch);
    k_probe<2><<<G, 256, 0, stream>>>(y0, aggu, Wr1, Wn1, pscr, psum, psq, N, nch);
    k_probe<3><<<G, 256, 0, stream>>>(y0, aggu, Wr1, Wn1, pscr, psum, psq, N, nch);
    k_probe4  <<<G, 256, 0, stream>>>(y0, aggu, Wr1, Wn1, pscr, psum, psq, N, nch);
}

// Round 7
// 402.650 us; speedup vs baseline: 1.2569x; 1.2569x over previous
//
#include <hip/hip_runtime.h>
#include <stdint.h>

// ResBlock: GraphConv(64->128) -> BN -> ReLU -> GraphConv(128->128) -> BN
//           + (x @ Wlin^T + blin) residual -> ReLU.
// Runtime dtype probe (bf16 vs f32).
// R15: probes removed. From R14's ablation: all probes + gemm1 < 60us
// (top-5 cutoff), aggs are the top at ~60-61us with a bandwidth-shaped
// signature (agg0 VALU 27% vs agg1 48%, same dur, same 177MB FETCH ->
// L2-miss path ~3TB/s is the common wall; latency vs BW unresolved).
//  - gemm1 -> direct-global P4 form (no LDS, no barriers; bounded <=
//    neutral by the R14 probe measurement).
//  - agg1 -> 2-nodes-per-wave paired gather (8 dwordx4 in flight, 32
//    distinct rows/wave-batch) to test the latency hypothesis.
//  - agg0 UNchanged = in-run control.
// Kept: PSH=8 binning, 4-deep agg0 batches, persistent gemm0/final with
// reg-prefetch, register BN stats + line-padded atomics, y0p pass.

#define CIN 64
#define COUT 128
#define BN_EPS 1e-5f
#define CURPAD 32              // ints: one 128B line per cursor
#define PCPAD 32               // ints: one 128B line per pcount entry
#define SPAD 32                // floats: one 128B line per stats channel
#define PSH 8                  // partition = dst >> PSH  (256 nodes)
#define PNODES (1 << PSH)
#define MAXP 512               // supports N <= 131072

typedef unsigned short u16;
typedef short short8 __attribute__((ext_vector_type(8)));
typedef float f32x4 __attribute__((ext_vector_type(4)));

__device__ __forceinline__ float bf2f(u16 u) {
    union { unsigned int i; float f; } v; v.i = ((unsigned int)u) << 16; return v.f;
}
__device__ __forceinline__ u16 f2bf(float f) {
    union { float f; unsigned int i; } v; v.f = f;
    unsigned int r = v.i + 0x7fffu + ((v.i >> 16) & 1u);  // RNE; finite inputs
    return (u16)(r >> 16);
}
__device__ __forceinline__ float lo16(unsigned int w) { return bf2f((u16)(w & 0xffffu)); }
__device__ __forceinline__ float hi16(unsigned int w) { return bf2f((u16)(w >> 16)); }

template<bool BF> __device__ __forceinline__ float ldf(const void* p, long i) {
    if (BF) return bf2f(((const u16*)p)[i]);
    return ((const float*)p)[i];
}
template<bool BF> __device__ __forceinline__ short8 ld8(const void* p, long i) {
    if (BF) return *(const short8*)((const u16*)p + i);
    const float* f = (const float*)p + i;
    short8 r;
#pragma unroll
    for (int j = 0; j < 8; ++j) r[j] = (short)f2bf(f[j]);
    return r;
}

__device__ __forceinline__ void acc8(float* a, uint4 w) {
    a[0] += lo16(w.x); a[1] += hi16(w.x);
    a[2] += lo16(w.y); a[3] += hi16(w.y);
    a[4] += lo16(w.z); a[5] += hi16(w.z);
    a[6] += lo16(w.w); a[7] += hi16(w.w);
}

// ---------------- dtype detection ----------------
__global__ void k_detect(const unsigned int* __restrict__ x, int* __restrict__ flag) {
    int lane = threadIdx.x;  // 64
    int cnt = 0;
#pragma unroll
    for (int i = 0; i < 8; ++i) {
        unsigned int w = x[lane * 8 + i];
        unsigned int e0 = (w >> 7) & 0xFFu, e1 = (w >> 23) & 0xFFu;
        cnt += (e0 >= 0x60u && e0 <= 0x8Eu);
        cnt += (e1 >= 0x60u && e1 <= 0x8Eu);
    }
    for (int o = 32; o; o >>= 1) cnt += __shfl_down(cnt, o);
    if (lane == 0) *flag = (cnt > 850) ? 1 : 0;   // 1 => bf16
}

// ---------------- partition build (partition = dst >> PSH) ----------------
__global__ __launch_bounds__(256) void k_phist(const int* __restrict__ dst,
                                               int* __restrict__ pcount, int E, int np) {
    __shared__ int h[MAXP];
    for (int i = threadIdx.x; i < np; i += 256) h[i] = 0;
    __syncthreads();
    int stride = gridDim.x * 256;
    for (int e = blockIdx.x * 256 + threadIdx.x; e < E; e += stride)
        atomicAdd(&h[dst[e] >> PSH], 1);
    __syncthreads();
    for (int i = threadIdx.x; i < np; i += 256)
        if (h[i]) atomicAdd(&pcount[i * PCPAD], h[i]);
}

__global__ void k_pscan(const int* __restrict__ pcount, int* __restrict__ pstart,
                        int* __restrict__ pcursor, int np, int E) {
    __shared__ int s[MAXP];
    int t = threadIdx.x;  // MAXP threads
    int v = (t < np) ? pcount[t * PCPAD] : 0;
    s[t] = v; __syncthreads();
    for (int o = 1; o < MAXP; o <<= 1) {
        int u = (t >= o) ? s[t - o] : 0;
        __syncthreads(); s[t] += u; __syncthreads();
    }
    if (t < np) {
        int ex = s[t] - v;
        pstart[t] = ex;
        pcursor[t * CURPAD] = ex;
    }
    if (t == 0) pstart[np] = E;
}

// One 4096-edge tile per block. rec = (dst & (PNODES-1)) << 20 | src
__global__ __launch_bounds__(256) void k_pfill(const int* __restrict__ src,
        const int* __restrict__ dst, int* __restrict__ pcursor,
        unsigned int* __restrict__ barr, int E, int np) {
    __shared__ int cnt[MAXP], gb[MAXP], loc[MAXP];
    int tid = threadIdx.x;
    int base = blockIdx.x * 4096;
    for (int i = tid; i < np; i += 256) { cnt[i] = 0; loc[i] = 0; }
    __syncthreads();
    int pk[16]; unsigned int rec[16];
#pragma unroll
    for (int k = 0; k < 16; ++k) {
        int e = base + k * 256 + tid;
        if (e < E) {
            int d = dst[e];
            pk[k] = d >> PSH;
            rec[k] = ((unsigned int)(d & (PNODES - 1)) << 20) | (unsigned int)src[e];
            atomicAdd(&cnt[pk[k]], 1);
        } else pk[k] = -1;
    }
    __syncthreads();
    for (int i = tid; i < np; i += 256)
        if (cnt[i]) gb[i] = atomicAdd(&pcursor[i * CURPAD], cnt[i]);
    __syncthreads();
#pragma unroll
    for (int k = 0; k < 16; ++k) {
        if (pk[k] >= 0) {
            int off = atomicAdd(&loc[pk[k]], 1);
            barr[gb[pk[k]] + off] = rec[k];
        }
    }
}

// Block per partition (PNODES=256): LDS counting sort -> csr + row_start.
__global__ __launch_bounds__(256) void k_psort(const unsigned int* __restrict__ barr,
        const int* __restrict__ pstart, int* __restrict__ csr,
        int* __restrict__ row_start, int n, int np, int E) {
    __shared__ int hist[PNODES], curs[PNODES], tsum[256];
    int tid = threadIdx.x;
    int p = blockIdx.x;
    int e0 = pstart[p], e1 = pstart[p + 1];
    int node0 = p << PSH;
    hist[tid] = 0;
    __syncthreads();
    for (int t = e0 + tid; t < e1; t += 256)
        atomicAdd(&hist[barr[t] >> 20], 1);
    __syncthreads();
    int v = hist[tid];
    tsum[tid] = v; __syncthreads();
    for (int o = 1; o < 256; o <<= 1) {
        int u = (tid >= o) ? tsum[tid - o] : 0;
        __syncthreads(); tsum[tid] += u; __syncthreads();
    }
    int ex = tsum[tid] - v;
    curs[tid] = ex;
    int nd = node0 + tid;
    if (nd < n) row_start[nd] = e0 + ex;
    if (p == np - 1 && tid == 0) row_start[n] = E;
    __syncthreads();
    for (int t = e0 + tid; t < e1; t += 256) {
        unsigned int rec = barr[t];
        int pos = atomicAdd(&curs[rec >> 20], 1);
        csr[e0 + pos] = (int)(rec & 0xFFFFF);
    }
}

// ------------- aggregation 0 (pull, wave/node, 4-deep slot gathers) -------
// UNCHANGED from R14 -- serves as the in-run control vs the paired agg1.
template<bool BF>
__device__ __forceinline__ void agg0_impl(const void* x, const int* rs, const int* csr,
                                          u16* agg, int n) {
    int i = blockIdx.x * 4 + (threadIdx.x >> 6);
    if (i >= n) return;
    int lane = threadIdx.x & 63;
    int slot = lane >> 4, cp = lane & 15;   // 4 slots x 16 lanes
    int b = rs[i], e = rs[i + 1];
    if (BF) {
        const unsigned int* x32 = (const unsigned int*)x;
        float acc[4] = {0.f, 0.f, 0.f, 0.f};
        int t = b + slot;
        for (; t + 12 < e; t += 16) {
            int j0 = csr[t], j1 = csr[t + 4], j2 = csr[t + 8], j3 = csr[t + 12];
            uint2 w0 = *((const uint2*)(x32 + (long)j0 * 32) + cp);
            uint2 w1 = *((const uint2*)(x32 + (long)j1 * 32) + cp);
            uint2 w2 = *((const uint2*)(x32 + (long)j2 * 32) + cp);
            uint2 w3 = *((const uint2*)(x32 + (long)j3 * 32) + cp);
            acc[0] += lo16(w0.x) + lo16(w1.x); acc[1] += hi16(w0.x) + hi16(w1.x);
            acc[2] += lo16(w0.y) + lo16(w1.y); acc[3] += hi16(w0.y) + hi16(w1.y);
            acc[0] += lo16(w2.x) + lo16(w3.x); acc[1] += hi16(w2.x) + hi16(w3.x);
            acc[2] += lo16(w2.y) + lo16(w3.y); acc[3] += hi16(w2.y) + hi16(w3.y);
        }
        for (; t < e; t += 4) {
            int j0 = csr[t];
            uint2 w0 = *((const uint2*)(x32 + (long)j0 * 32) + cp);
            acc[0] += lo16(w0.x); acc[1] += hi16(w0.x);
            acc[2] += lo16(w0.y); acc[3] += hi16(w0.y);
        }
#pragma unroll
        for (int k = 0; k < 4; ++k) {
            acc[k] += __shfl_xor(acc[k], 16);
            acc[k] += __shfl_xor(acc[k], 32);
        }
        if (slot == 0) {
            uint2 o;
            o.x = (unsigned int)f2bf(acc[0]) | ((unsigned int)f2bf(acc[1]) << 16);
            o.y = (unsigned int)f2bf(acc[2]) | ((unsigned int)f2bf(acc[3]) << 16);
            *((uint2*)((unsigned int*)agg + (long)i * 32) + cp) = o;
        }
    } else {
        float acc[4] = {0.f, 0.f, 0.f, 0.f};
        int t = b + slot;
        for (; t + 12 < e; t += 16) {
            int j0 = csr[t], j1 = csr[t + 4], j2 = csr[t + 8], j3 = csr[t + 12];
            float4 w0 = *((const float4*)((const float*)x + (long)j0 * 64) + cp);
            float4 w1 = *((const float4*)((const float*)x + (long)j1 * 64) + cp);
            float4 w2 = *((const float4*)((const float*)x + (long)j2 * 64) + cp);
            float4 w3 = *((const float4*)((const float*)x + (long)j3 * 64) + cp);
            acc[0] += (w0.x + w1.x) + (w2.x + w3.x);
            acc[1] += (w0.y + w1.y) + (w2.y + w3.y);
            acc[2] += (w0.z + w1.z) + (w2.z + w3.z);
            acc[3] += (w0.w + w1.w) + (w2.w + w3.w);
        }
        for (; t < e; t += 4) {
            int j0 = csr[t];
            float4 w0 = *((const float4*)((const float*)x + (long)j0 * 64) + cp);
            acc[0] += w0.x; acc[1] += w0.y; acc[2] += w0.z; acc[3] += w0.w;
        }
#pragma unroll
        for (int k = 0; k < 4; ++k) {
            acc[k] += __shfl_xor(acc[k], 16);
            acc[k] += __shfl_xor(acc[k], 32);
        }
        if (slot == 0) {
            uint2 o;
            o.x = (unsigned int)f2bf(acc[0]) | ((unsigned int)f2bf(acc[1]) << 16);
            o.y = (unsigned int)f2bf(acc[2]) | ((unsigned int)f2bf(acc[3]) << 16);
            *((uint2*)((unsigned int*)agg + (long)i * 32) + cp) = o;
        }
    }
}

__global__ __launch_bounds__(256) void k_agg0(const int* __restrict__ flag,
        const void* x, const int* __restrict__ rs, const int* __restrict__ csr,
        u16* __restrict__ agg, int n) {
    if (*flag) agg0_impl<true >(x, rs, csr, agg, n);
    else       agg0_impl<false>(x, rs, csr, agg, n);
}

// ---- y0p = relu(bn0(y0)) materialized IN-PLACE (bf16), streaming --------
__global__ __launch_bounds__(256) void k_y0p(unsigned int* __restrict__ y0,
        const float* __restrict__ sc, const float* __restrict__ sh, long nq) {
    long idx = (long)blockIdx.x * 256 + threadIdx.x;
    int colq = threadIdx.x & 15;
    float s8[8], h8[8];
#pragma unroll
    for (int j = 0; j < 8; ++j) { s8[j] = sc[colq * 8 + j]; h8[j] = sh[colq * 8 + j]; }
    long stride = (long)gridDim.x * 256;
    uint4* p = (uint4*)y0;
    for (; idx < nq; idx += stride) {
        uint4 w = p[idx];
        unsigned int r[4] = {w.x, w.y, w.z, w.w};
        uint4 o;
        unsigned int* po = (unsigned int*)&o;
#pragma unroll
        for (int d = 0; d < 4; ++d) {
            float a = fmaxf(lo16(r[d]) * s8[2 * d]     + h8[2 * d],     0.f);
            float b = fmaxf(hi16(r[d]) * s8[2 * d + 1] + h8[2 * d + 1], 0.f);
            po[d] = (unsigned int)f2bf(a) | ((unsigned int)f2bf(b) << 16);
        }
        p[idx] = o;
    }
}

// ------- aggregation 1: 2 nodes per wave, paired 4-deep gathers ----------
// Doubles in-flight row loads (8 dwordx4 issued back-to-back per batch).
__global__ __launch_bounds__(256) void k_agg1(const u16* __restrict__ y0p,
        const int* __restrict__ rs, const int* __restrict__ csr,
        u16* __restrict__ agg, int n) {
    int i0 = blockIdx.x * 8 + ((threadIdx.x >> 6) << 1);
    if (i0 >= n) return;
    int lane = threadIdx.x & 63;
    int slot = lane >> 4, cp = lane & 15;   // y0p row = 256B = 16 x uint4
    const unsigned int* y32 = (const unsigned int*)y0p;
    int i1 = i0 + 1;
    int bA = rs[i0], eA = rs[i0 + 1];
    int bB = eA, eB = (i1 < n) ? rs[i1 + 1] : eA;   // rows contiguous in csr

    float aA[8] = {0.f, 0.f, 0.f, 0.f, 0.f, 0.f, 0.f, 0.f};
    float aB[8] = {0.f, 0.f, 0.f, 0.f, 0.f, 0.f, 0.f, 0.f};
    int tA = bA + slot, tB = bB + slot;

    // paired phase: 4 A-loads + 4 B-loads in flight together
    while (tA + 12 < eA && tB + 12 < eB) {
        int ja0 = csr[tA], ja1 = csr[tA + 4], ja2 = csr[tA + 8], ja3 = csr[tA + 12];
        int jb0 = csr[tB], jb1 = csr[tB + 4], jb2 = csr[tB + 8], jb3 = csr[tB + 12];
        uint4 wa0 = *((const uint4*)(y32 + (long)ja0 * 64) + cp);
        uint4 wa1 = *((const uint4*)(y32 + (long)ja1 * 64) + cp);
        uint4 wa2 = *((const uint4*)(y32 + (long)ja2 * 64) + cp);
        uint4 wa3 = *((const uint4*)(y32 + (long)ja3 * 64) + cp);
        uint4 wb0 = *((const uint4*)(y32 + (long)jb0 * 64) + cp);
        uint4 wb1 = *((const uint4*)(y32 + (long)jb1 * 64) + cp);
        uint4 wb2 = *((const uint4*)(y32 + (long)jb2 * 64) + cp);
        uint4 wb3 = *((const uint4*)(y32 + (long)jb3 * 64) + cp);
        acc8(aA, wa0); acc8(aA, wa1); acc8(aA, wa2); acc8(aA, wa3);
        acc8(aB, wb0); acc8(aB, wb1); acc8(aB, wb2); acc8(aB, wb3);
        tA += 16; tB += 16;
    }
    // drain A
    for (; tA + 12 < eA; tA += 16) {
        int j0 = csr[tA], j1 = csr[tA + 4], j2 = csr[tA + 8], j3 = csr[tA + 12];
        uint4 w0 = *((const uint4*)(y32 + (long)j0 * 64) + cp);
        uint4 w1 = *((const uint4*)(y32 + (long)j1 * 64) + cp);
        uint4 w2 = *((const uint4*)(y32 + (long)j2 * 64) + cp);
        uint4 w3 = *((const uint4*)(y32 + (long)j3 * 64) + cp);
        acc8(aA, w0); acc8(aA, w1); acc8(aA, w2); acc8(aA, w3);
    }
    for (; tA < eA; tA += 4) {
        uint4 w0 = *((const uint4*)(y32 + (long)csr[tA] * 64) + cp);
        acc8(aA, w0);
    }
    // drain B
    for (; tB + 12 < eB; tB += 16) {
        int j0 = csr[tB], j1 = csr[tB + 4], j2 = csr[tB + 8], j3 = csr[tB + 12];
        uint4 w0 = *((const uint4*)(y32 + (long)j0 * 64) + cp);
        uint4 w1 = *((const uint4*)(y32 + (long)j1 * 64) + cp);
        uint4 w2 = *((const uint4*)(y32 + (long)j2 * 64) + cp);
        uint4 w3 = *((const uint4*)(y32 + (long)j3 * 64) + cp);
        acc8(aB, w0); acc8(aB, w1); acc8(aB, w2); acc8(aB, w3);
    }
    for (; tB < eB; tB += 4) {
        uint4 w0 = *((const uint4*)(y32 + (long)csr[tB] * 64) + cp);
        acc8(aB, w0);
    }
#pragma unroll
    for (int k = 0; k < 8; ++k) {
        aA[k] += __shfl_xor(aA[k], 16);
        aA[k] += __shfl_xor(aA[k], 32);
        aB[k] += __shfl_xor(aB[k], 16);
        aB[k] += __shfl_xor(aB[k], 32);
    }
    if (slot == 0) {
        uint4 o;
        o.x = (unsigned int)f2bf(aA[0]) | ((unsigned int)f2bf(aA[1]) << 16);
        o.y = (unsigned int)f2bf(aA[2]) | ((unsigned int)f2bf(aA[3]) << 16);
        o.z = (unsigned int)f2bf(aA[4]) | ((unsigned int)f2bf(aA[5]) << 16);
        o.w = (unsigned int)f2bf(aA[6]) | ((unsigned int)f2bf(aA[7]) << 16);
        *((uint4*)((unsigned int*)agg + (long)i0 * 64) + cp) = o;
        if (i1 < n) {
            uint4 p;
            p.x = (unsigned int)f2bf(aB[0]) | ((unsigned int)f2bf(aB[1]) << 16);
            p.y = (unsigned int)f2bf(aB[2]) | ((unsigned int)f2bf(aB[3]) << 16);
            p.z = (unsigned int)f2bf(aB[4]) | ((unsigned int)f2bf(aB[5]) << 16);
            p.w = (unsigned int)f2bf(aB[6]) | ((unsigned int)f2bf(aB[7]) << 16);
            *((uint4*)((unsigned int*)agg + (long)i1 * 64) + cp) = p;
        }
    }
}

// ---------------- GEMM0: y0 = [x|agg0] @ [Wr0;Wn0]^T, fused stats ----------
template<bool BF>
__device__ __forceinline__ void gemm0_impl(const void* x, const u16* agg,
                                           const void* Wr, const void* Wn,
                                           u16* y0, float* sumP, float* sqP,
                                           int n, int nch, u16* lds) {
    const int ST = 130;
    int tid = threadIdx.x;
    int wave = tid >> 6, lane = tid & 63, lr = lane & 15, q = lane >> 4;

    short8 wf[2][4];
#pragma unroll
    for (int i = 0; i < 2; ++i) {
        int c = (2 * wave + i) * 16 + lr;
#pragma unroll
        for (int ks = 0; ks < 4; ++ks) {
            const void* W = (ks < 2) ? Wr : Wn;
            wf[i][ks] = ld8<BF>(W, (long)c * CIN + (ks & 1) * 32 + q * 8);
        }
    }

    const int rowb = tid >> 3, wb = tid & 7;
    const int rowf = tid >> 4, wfc = tid & 15;
    short8 rbx[2]; float4 rfx[4]; short8 rag[2];

    auto regload = [&](long chunk0) {
        if (BF) {
#pragma unroll
            for (int i = 0; i < 2; ++i) {
                long rg = chunk0 + rowb + i * 32; if (rg > n - 1) rg = n - 1;
                rbx[i] = *(const short8*)((const u16*)x + rg * CIN + wb * 8);
            }
        } else {
#pragma unroll
            for (int i = 0; i < 4; ++i) {
                long rg = chunk0 + rowf + i * 16; if (rg > n - 1) rg = n - 1;
                rfx[i] = *(const float4*)((const float*)x + rg * CIN + wfc * 4);
            }
        }
#pragma unroll
        for (int i = 0; i < 2; ++i) {
            long rg = chunk0 + rowb + i * 32; if (rg > n - 1) rg = n - 1;
            rag[i] = *(const short8*)(agg + rg * CIN + wb * 8);
        }
    };

    float st[2] = {0.f, 0.f}, sq[2] = {0.f, 0.f};
    int ch = blockIdx.x;
    if (ch < nch) regload((long)ch * 64);
    for (; ch < nch; ch += gridDim.x) {
        long chunk0 = (long)ch * 64;
        __syncthreads();
        if (BF) {
#pragma unroll
            for (int i = 0; i < 2; ++i)
                *(short8*)(lds + (rowb + i * 32) * ST + wb * 8) = rbx[i];
        } else {
#pragma unroll
            for (int i = 0; i < 4; ++i) {
                u16* d = lds + (rowf + i * 16) * ST + wfc * 4;
                d[0] = f2bf(rfx[i].x); d[1] = f2bf(rfx[i].y);
                d[2] = f2bf(rfx[i].z); d[3] = f2bf(rfx[i].w);
            }
        }
#pragma unroll
        for (int i = 0; i < 2; ++i)
            *(short8*)(lds + (rowb + i * 32) * ST + 64 + wb * 8) = rag[i];
        __syncthreads();
        long nxt = (long)ch + gridDim.x;
        if (nxt < nch) regload(nxt * 64);

#pragma unroll
        for (int t = 0; t < 4; ++t) {
            short8 a[4];
#pragma unroll
            for (int ks = 0; ks < 4; ++ks)
                a[ks] = *(const short8*)(lds + (t * 16 + lr) * ST + ks * 32 + q * 8);
#pragma unroll
            for (int i = 0; i < 2; ++i) {
                f32x4 acc = {0.f, 0.f, 0.f, 0.f};
#pragma unroll
                for (int ks = 0; ks < 4; ++ks)
                    acc = __builtin_amdgcn_mfma_f32_16x16x32_bf16(a[ks], wf[i][ks], acc, 0, 0, 0);
                int c = (2 * wave + i) * 16 + lr;
#pragma unroll
                for (int r = 0; r < 4; ++r) {
                    long row = chunk0 + t * 16 + q * 4 + r;
                    if (row < n) {
                        y0[row * COUT + c] = f2bf(acc[r]);   // b0 cancels in BN
                        st[i] += acc[r]; sq[i] += acc[r] * acc[r];
                    }
                }
            }
        }
    }
#pragma unroll
    for (int i = 0; i < 2; ++i) {
        st[i] += __shfl_xor(st[i], 16); st[i] += __shfl_xor(st[i], 32);
        sq[i] += __shfl_xor(sq[i], 16); sq[i] += __shfl_xor(sq[i], 32);
    }
    if (q == 0) {
#pragma unroll
        for (int i = 0; i < 2; ++i) {
            int c = (2 * wave + i) * 16 + lr;
            atomicAdd(&sumP[c * SPAD], st[i]);
            atomicAdd(&sqP[c * SPAD], sq[i]);
        }
    }
}

__global__ __launch_bounds__(256) void k_gemm0(const int* __restrict__ flag,
        const void* x, const u16* __restrict__ agg, const void* Wr, const void* Wn,
        u16* __restrict__ y0, float* __restrict__ sumP, float* __restrict__ sqP,
        int n, int nch) {
    __shared__ u16 lds[64 * 130];
    if (*flag) gemm0_impl<true >(x, agg, Wr, Wn, y0, sumP, sqP, n, nch, lds);
    else       gemm0_impl<false>(x, agg, Wr, Wn, y0, sumP, sqP, n, nch, lds);
}

// ------ GEMM1 (direct-global form): y1 = [y0p|agg1] @ [Wr1;Wn1]^T ---------
// No LDS, no barriers: each lane loads its MFMA A-fragments straight from
// global (same operand mapping as the LDS version; verified in R14's P4).
template<bool BF>
__device__ __forceinline__ void gemm1_impl(const u16* y0p, const u16* agg,
                                           const void* Wr, const void* Wn,
                                           u16* y1, float* sumP, float* sqP,
                                           int n, int nch) {
    int tid = threadIdx.x;
    int wave = tid >> 6, lane = tid & 63, lr = lane & 15, q = lane >> 4;

    short8 wf[2][8];
#pragma unroll
    for (int i = 0; i < 2; ++i) {
        int c = (2 * wave + i) * 16 + lr;
#pragma unroll
        for (int ks = 0; ks < 8; ++ks) {
            const void* W = (ks < 4) ? Wr : Wn;
            wf[i][ks] = ld8<BF>(W, (long)c * COUT + (ks & 3) * 32 + q * 8);
        }
    }

    float st[2] = {0.f, 0.f}, sq[2] = {0.f, 0.f};
    for (int ch = blockIdx.x; ch < nch; ch += gridDim.x) {
        long chunk0 = (long)ch * 64;
#pragma unroll
        for (int t = 0; t < 4; ++t) {
            long rg = chunk0 + t * 16 + lr; if (rg > n - 1) rg = n - 1;
            short8 a[8];
#pragma unroll
            for (int ks = 0; ks < 4; ++ks)
                a[ks] = *(const short8*)(y0p + rg * COUT + ks * 32 + q * 8);
#pragma unroll
            for (int ks = 0; ks < 4; ++ks)
                a[4 + ks] = *(const short8*)(agg + rg * COUT + ks * 32 + q * 8);
#pragma unroll
            for (int i = 0; i < 2; ++i) {
                f32x4 acc = {0.f, 0.f, 0.f, 0.f};
#pragma unroll
                for (int ks = 0; ks < 8; ++ks)
                    acc = __builtin_amdgcn_mfma_f32_16x16x32_bf16(a[ks], wf[i][ks], acc, 0, 0, 0);
                int c = (2 * wave + i) * 16 + lr;
#pragma unroll
                for (int r = 0; r < 4; ++r) {
                    long row = chunk0 + t * 16 + q * 4 + r;
                    if (row < n) {
                        y1[row * COUT + c] = f2bf(acc[r]);   // b1 cancels in BN
                        st[i] += acc[r]; sq[i] += acc[r] * acc[r];
                    }
                }
            }
        }
    }
#pragma unroll
    for (int i = 0; i < 2; ++i) {
        st[i] += __shfl_xor(st[i], 16); st[i] += __shfl_xor(st[i], 32);
        sq[i] += __shfl_xor(sq[i], 16); sq[i] += __shfl_xor(sq[i], 32);
    }
    if (q == 0) {
#pragma unroll
        for (int i = 0; i < 2; ++i) {
            int c = (2 * wave + i) * 16 + lr;
            atomicAdd(&sumP[c * SPAD], st[i]);
            atomicAdd(&sqP[c * SPAD], sq[i]);
        }
    }
}

__global__ __launch_bounds__(256) void k_gemm1(const int* __restrict__ flag,
        const u16* __restrict__ y0p, const u16* __restrict__ agg,
        const void* Wr, const void* Wn,
        u16* y1_bf /*=d_out*/, u16* y1_ws,
        float* __restrict__ sumP, float* __restrict__ sqP, int n, int nch) {
    u16* y1 = *flag ? y1_bf : y1_ws;
    if (*flag) gemm1_impl<true >(y0p, agg, Wr, Wn, y1, sumP, sqP, n, nch);
    else       gemm1_impl<false>(y0p, agg, Wr, Wn, y1, sumP, sqP, n, nch);
}

// ---------------- BN finalize (reads line-padded stats) ----------------
__global__ void k_bnfin(const int* __restrict__ flag,
                        const float* __restrict__ sumP, const float* __restrict__ sqP,
                        const void* g, const void* be,
                        float* __restrict__ scale, float* __restrict__ shift, int n) {
    int c = threadIdx.x;
    bool bf = (*flag != 0);
    float inv = 1.f / (float)n;
    float mu = sumP[c * SPAD] * inv;
    float var = fmaxf(sqP[c * SPAD] * inv - mu * mu, 0.f);
    float gv = bf ? bf2f(((const u16*)g)[c]) : ((const float*)g)[c];
    float bv = bf ? bf2f(((const u16*)be)[c]) : ((const float*)be)[c];
    float sc = gv * rsqrtf(var + BN_EPS);
    scale[c] = sc;
    shift[c] = bv - mu * sc;
}

// ---------------- final: out = relu(bn1(y1) + x@Wlin^T + blin) ------------
template<bool BF>
__device__ __forceinline__ void final_impl(const void* x, const u16* y1,
                                           const void* Wlin, const void* blin,
                                           const float* sc, const float* sh,
                                           void* out, int n, int nch, u16* lds) {
    const int ST = 194;
    int tid = threadIdx.x;
    int wave = tid >> 6, lane = tid & 63, lr = lane & 15, q = lane >> 4;

    short8 wf[2][2];
    float blc[2], scc[2], shc[2];
#pragma unroll
    for (int i = 0; i < 2; ++i) {
        int c = (2 * wave + i) * 16 + lr;
#pragma unroll
        for (int ks = 0; ks < 2; ++ks)
            wf[i][ks] = ld8<BF>(Wlin, (long)c * CIN + ks * 32 + q * 8);
        blc[i] = ldf<BF>(blin, c);
        scc[i] = sc[c]; shc[i] = sh[c];
    }

    const int rowb = tid >> 3, wb = tid & 7;
    const int rowf = tid >> 4, wfc = tid & 15;
    const int rowy = tid >> 4, wy = tid & 15;
    short8 rbx[2]; float4 rfx[4]; short8 ry[4];

    auto regload = [&](long chunk0) {
        if (BF) {
#pragma unroll
            for (int i = 0; i < 2; ++i) {
                long rg = chunk0 + rowb + i * 32; if (rg > n - 1) rg = n - 1;
                rbx[i] = *(const short8*)((const u16*)x + rg * CIN + wb * 8);
            }
        } else {
#pragma unroll
            for (int i = 0; i < 4; ++i) {
                long rg = chunk0 + rowf + i * 16; if (rg > n - 1) rg = n - 1;
                rfx[i] = *(const float4*)((const float*)x + rg * CIN + wfc * 4);
            }
        }
#pragma unroll
        for (int i = 0; i < 4; ++i) {
            long rg = chunk0 + rowy + i * 16; if (rg > n - 1) rg = n - 1;
            ry[i] = *(const short8*)(y1 + rg * COUT + wy * 8);
        }
    };

    int ch = blockIdx.x;
    if (ch < nch) regload((long)ch * 64);
    for (; ch < nch; ch += gridDim.x) {
        long chunk0 = (long)ch * 64;
        __syncthreads();
        if (BF) {
#pragma unroll
            for (int i = 0; i < 2; ++i)
                *(short8*)(lds + (rowb + i * 32) * ST + wb * 8) = rbx[i];
        } else {
#pragma unroll
            for (int i = 0; i < 4; ++i) {
                u16* d = lds + (rowf + i * 16) * ST + wfc * 4;
                d[0] = f2bf(rfx[i].x); d[1] = f2bf(rfx[i].y);
                d[2] = f2bf(rfx[i].z); d[3] = f2bf(rfx[i].w);
            }
        }
#pragma unroll
        for (int i = 0; i < 4; ++i)
            *(short8*)(lds + (rowy + i * 16) * ST + 64 + wy * 8) = ry[i];
        __syncthreads();
        long nxt = (long)ch + gridDim.x;
        if (nxt < nch) regload(nxt * 64);

#pragma unroll
        for (int t = 0; t < 4; ++t) {
            short8 a[2];
#pragma unroll
            for (int ks = 0; ks < 2; ++ks)
                a[ks] = *(const short8*)(lds + (t * 16 + lr) * ST + ks * 32 + q * 8);
#pragma unroll
            for (int i = 0; i < 2; ++i) {
                f32x4 acc = {0.f, 0.f, 0.f, 0.f};
                acc = __builtin_amdgcn_mfma_f32_16x16x32_bf16(a[0], wf[i][0], acc, 0, 0, 0);
                acc = __builtin_amdgcn_mfma_f32_16x16x32_bf16(a[1], wf[i][1], acc, 0, 0, 0);
                int c = (2 * wave + i) * 16 + lr;
#pragma unroll
                for (int r = 0; r < 4; ++r) {
                    long row = chunk0 + t * 16 + q * 4 + r;
                    if (row < n) {
                        float yv = bf2f(lds[(t * 16 + q * 4 + r) * ST + 64 + c]);
                        float v = acc[r] + blc[i] + yv * scc[i] + shc[i];
                        v = fmaxf(v, 0.f);
                        if (BF) ((u16*)out)[row * COUT + c] = f2bf(v);
                        else    ((float*)out)[row * COUT + c] = v;
                    }
                }
            }
        }
    }
}

__global__ __launch_bounds__(256) void k_final(const int* __restrict__ flag,
        const void* x, const void* Wlin, const void* blin,
        const u16* y1_bf /*=d_out*/, const u16* y1_ws,
        const float* __restrict__ sc, const float* __restrict__ sh,
        void* out, int n, int nch) {
    __shared__ u16 lds[64 * 194];
    const u16* y1 = *flag ? y1_bf : y1_ws;
    if (*flag) final_impl<true >(x, y1, Wlin, blin, sc, sh, out, n, nch, lds);
    else       final_impl<false>(x, y1, Wlin, blin, sc, sh, out, n, nch, lds);
}

extern "C" void kernel_launch(void* const* d_in, const int* in_sizes, int n_in,
                              void* d_out, int out_size, void* d_ws, size_t ws_size,
                              hipStream_t stream) {
    (void)n_in; (void)out_size; (void)ws_size;
    const void* x    = d_in[0];
    const int*  ei   = (const int*)d_in[1];
    const void* Wr0  = d_in[2];
    const void* Wn0  = d_in[3];
    /* b0 dropped: BN-invariant */
    const void* g0   = d_in[5];
    const void* be0  = d_in[6];
    const void* Wr1  = d_in[7];
    const void* Wn1  = d_in[8];
    /* b1 dropped */
    const void* g1   = d_in[10];
    const void* be1  = d_in[11];
    const void* Wlin = d_in[12];
    const void* blin = d_in[13];

    const int N = in_sizes[0] / CIN;
    const int E = in_sizes[1] / 2;
    const int* src = ei;
    const int* dst = ei + E;
    const int NP = (N + PNODES - 1) >> PSH;

    // ---- workspace carve (256B aligned); f32-only region LAST ----
    char* base = (char*)d_ws;
    size_t off = 0;
    auto carve = [&](size_t bytes) -> void* {
        void* p = base + off;
        off = (off + bytes + 255) & ~(size_t)255;
        return p;
    };
    int*   flag      = (int*)carve(256);
    int*   pcount    = (int*)carve(MAXP * PCPAD * sizeof(int));
    int*   pstart    = (int*)carve((MAXP + 1) * sizeof(int));
    int*   pcursor   = (int*)carve(MAXP * CURPAD * sizeof(int));
    float* statsP    = (float*)carve(4 * 128 * SPAD * sizeof(float));
    float* scsh      = (float*)carve(512 * sizeof(float));
    int*   row_start = (int*)carve((size_t)(N + 1) * sizeof(int));
    unsigned int* barr = (unsigned int*)carve((size_t)E * sizeof(int));
    int*   csr       = (int*)carve((size_t)E * sizeof(int));
    u16*   aggu      = (u16*)carve((size_t)N * COUT * sizeof(u16));
    u16*   y0        = (u16*)carve((size_t)N * COUT * sizeof(u16));
    u16*   y1_ws     = (u16*)carve((size_t)N * COUT * sizeof(u16));

    float* sum0P = statsP;
    float* sq0P  = statsP + 128 * SPAD;
    float* sum1P = statsP + 256 * SPAD;
    float* sq1P  = statsP + 384 * SPAD;

    hipMemsetAsync(pcount, 0, MAXP * PCPAD * sizeof(int), stream);
    hipMemsetAsync(statsP, 0, 4 * 128 * SPAD * sizeof(float), stream);

    const int nwb = (N + 3) / 4;        // agg0 wave-per-node blocks
    const int nwb2 = (N + 7) / 8;       // agg1 2-node-per-wave blocks
    const int nch = (N + 63) / 64;
    const int ntl = (E + 4095) / 4096;
    const int G   = nch < 1024 ? nch : 1024;
    const long nq = (long)N * 16;
    int g2 = (int)((nq + 255) / 256); if (g2 > 2048) g2 = 2048;

    k_detect<<<1, 64, 0, stream>>>((const unsigned int*)x, flag);

    k_phist<<<256, 256, 0, stream>>>(dst, pcount, E, NP);
    k_pscan<<<1, MAXP, 0, stream>>>(pcount, pstart, pcursor, NP, E);
    k_pfill<<<ntl, 256, 0, stream>>>(src, dst, pcursor, barr, E, NP);
    k_psort<<<NP, 256, 0, stream>>>(barr, pstart, csr, row_start, N, NP, E);

    k_agg0 <<<nwb, 256, 0, stream>>>(flag, x, row_start, csr, aggu, N);
    k_gemm0<<<G, 256, 0, stream>>>(flag, x, aggu, Wr0, Wn0, y0,
                                   sum0P, sq0P, N, nch);
    k_bnfin<<<1, 128, 0, stream>>>(flag, sum0P, sq0P, g0, be0,
                                   scsh, scsh + 128, N);

    k_y0p<<<g2, 256, 0, stream>>>((unsigned int*)y0, scsh, scsh + 128, nq);

    k_agg1 <<<nwb2, 256, 0, stream>>>(y0, row_start, csr, aggu, N);
    k_gemm1<<<G, 256, 0, stream>>>(flag, y0, aggu, Wr1, Wn1,
                                   (u16*)d_out, y1_ws, sum1P, sq1P, N, nch);
    k_bnfin<<<1, 128, 0, stream>>>(flag, sum1P, sq1P, g1, be1,
                                   scsh + 256, scsh + 384, N);

    k_final<<<G, 256, 0, stream>>>(flag, x, Wlin, blin,
                                   (const u16*)d_out, y1_ws,
                                   scsh + 256, scsh + 384, d_out, N, nch);
}

// Round 8
// 393.124 us; speedup vs baseline: 1.2873x; 1.0242x over previous
//
#include <hip/hip_runtime.h>
#include <stdint.h>

// ResBlock: GraphConv(64->128) -> BN -> ReLU -> GraphConv(128->128) -> BN
//           + (x @ Wlin^T + blin) residual -> ReLU.
// Runtime dtype probe (bf16 vs f32).
// R16: inputs are f32 (flag=0) -> agg0 was gathering 256B f32 rows (same
// 177MB FETCH as agg1). Fixes:
//  - k_xbf: materialize xb = bf16(x) once (~38MB stream) -> agg0 gathers
//    128B rows (half the bytes). Pre-committed read: FETCH halves + dur
//    ~35us => aggs BW-bound (wall confirmed); dur stays 60 => latency.
//  - agg1 reverted to R14 4-deep single-node form (pairing regressed:
//    VGPR 28->44, occ 69->43%, serial drains).
//  - gemm0 -> direct-global from xb (isomorphic to verified gemm1-direct);
//    final's x-feed direct from xb, LDS keeps only y1 (ST 194->130).
// Kept: gemm1 direct-global (paid ~-14us in R15), PSH=8 binning, persistent
// grids, register BN stats + line-padded atomics, y0p pass.

#define CIN 64
#define COUT 128
#define BN_EPS 1e-5f
#define CURPAD 32              // ints: one 128B line per cursor
#define PCPAD 32               // ints: one 128B line per pcount entry
#define SPAD 32                // floats: one 128B line per stats channel
#define PSH 8                  // partition = dst >> PSH  (256 nodes)
#define PNODES (1 << PSH)
#define MAXP 512               // supports N <= 131072

typedef unsigned short u16;
typedef short short8 __attribute__((ext_vector_type(8)));
typedef float f32x4 __attribute__((ext_vector_type(4)));

__device__ __forceinline__ float bf2f(u16 u) {
    union { unsigned int i; float f; } v; v.i = ((unsigned int)u) << 16; return v.f;
}
__device__ __forceinline__ u16 f2bf(float f) {
    union { float f; unsigned int i; } v; v.f = f;
    unsigned int r = v.i + 0x7fffu + ((v.i >> 16) & 1u);  // RNE; finite inputs
    return (u16)(r >> 16);
}
__device__ __forceinline__ float lo16(unsigned int w) { return bf2f((u16)(w & 0xffffu)); }
__device__ __forceinline__ float hi16(unsigned int w) { return bf2f((u16)(w >> 16)); }

template<bool BF> __device__ __forceinline__ float ldf(const void* p, long i) {
    if (BF) return bf2f(((const u16*)p)[i]);
    return ((const float*)p)[i];
}
template<bool BF> __device__ __forceinline__ short8 ld8(const void* p, long i) {
    if (BF) return *(const short8*)((const u16*)p + i);
    const float* f = (const float*)p + i;
    short8 r;
#pragma unroll
    for (int j = 0; j < 8; ++j) r[j] = (short)f2bf(f[j]);
    return r;
}

__device__ __forceinline__ void acc8(float* a, uint4 w) {
    a[0] += lo16(w.x); a[1] += hi16(w.x);
    a[2] += lo16(w.y); a[3] += hi16(w.y);
    a[4] += lo16(w.z); a[5] += hi16(w.z);
    a[6] += lo16(w.w); a[7] += hi16(w.w);
}

// ---------------- dtype detection ----------------
__global__ void k_detect(const unsigned int* __restrict__ x, int* __restrict__ flag) {
    int lane = threadIdx.x;  // 64
    int cnt = 0;
#pragma unroll
    for (int i = 0; i < 8; ++i) {
        unsigned int w = x[lane * 8 + i];
        unsigned int e0 = (w >> 7) & 0xFFu, e1 = (w >> 23) & 0xFFu;
        cnt += (e0 >= 0x60u && e0 <= 0x8Eu);
        cnt += (e1 >= 0x60u && e1 <= 0x8Eu);
    }
    for (int o = 32; o; o >>= 1) cnt += __shfl_down(cnt, o);
    if (lane == 0) *flag = (cnt > 850) ? 1 : 0;   // 1 => bf16
}

// ---- xb = bf16(x), materialized once (copy if already bf16) --------------
__global__ __launch_bounds__(256) void k_xbf(const int* __restrict__ flag,
        const void* __restrict__ x, u16* __restrict__ xb, long n8) {
    long idx = (long)blockIdx.x * 256 + threadIdx.x;
    long stride = (long)gridDim.x * 256;
    uint4* dst = (uint4*)xb;
    if (*flag) {
        const uint4* src = (const uint4*)x;
        for (; idx < n8; idx += stride) dst[idx] = src[idx];
    } else {
        const float4* src = (const float4*)x;
        for (; idx < n8; idx += stride) {
            float4 a = src[idx * 2], b = src[idx * 2 + 1];
            uint4 o;
            o.x = (unsigned int)f2bf(a.x) | ((unsigned int)f2bf(a.y) << 16);
            o.y = (unsigned int)f2bf(a.z) | ((unsigned int)f2bf(a.w) << 16);
            o.z = (unsigned int)f2bf(b.x) | ((unsigned int)f2bf(b.y) << 16);
            o.w = (unsigned int)f2bf(b.z) | ((unsigned int)f2bf(b.w) << 16);
            dst[idx] = o;
        }
    }
}

// ---------------- partition build (partition = dst >> PSH) ----------------
__global__ __launch_bounds__(256) void k_phist(const int* __restrict__ dst,
                                               int* __restrict__ pcount, int E, int np) {
    __shared__ int h[MAXP];
    for (int i = threadIdx.x; i < np; i += 256) h[i] = 0;
    __syncthreads();
    int stride = gridDim.x * 256;
    for (int e = blockIdx.x * 256 + threadIdx.x; e < E; e += stride)
        atomicAdd(&h[dst[e] >> PSH], 1);
    __syncthreads();
    for (int i = threadIdx.x; i < np; i += 256)
        if (h[i]) atomicAdd(&pcount[i * PCPAD], h[i]);
}

__global__ void k_pscan(const int* __restrict__ pcount, int* __restrict__ pstart,
                        int* __restrict__ pcursor, int np, int E) {
    __shared__ int s[MAXP];
    int t = threadIdx.x;  // MAXP threads
    int v = (t < np) ? pcount[t * PCPAD] : 0;
    s[t] = v; __syncthreads();
    for (int o = 1; o < MAXP; o <<= 1) {
        int u = (t >= o) ? s[t - o] : 0;
        __syncthreads(); s[t] += u; __syncthreads();
    }
    if (t < np) {
        int ex = s[t] - v;
        pstart[t] = ex;
        pcursor[t * CURPAD] = ex;
    }
    if (t == 0) pstart[np] = E;
}

// One 4096-edge tile per block. rec = (dst & (PNODES-1)) << 20 | src
__global__ __launch_bounds__(256) void k_pfill(const int* __restrict__ src,
        const int* __restrict__ dst, int* __restrict__ pcursor,
        unsigned int* __restrict__ barr, int E, int np) {
    __shared__ int cnt[MAXP], gb[MAXP], loc[MAXP];
    int tid = threadIdx.x;
    int base = blockIdx.x * 4096;
    for (int i = tid; i < np; i += 256) { cnt[i] = 0; loc[i] = 0; }
    __syncthreads();
    int pk[16]; unsigned int rec[16];
#pragma unroll
    for (int k = 0; k < 16; ++k) {
        int e = base + k * 256 + tid;
        if (e < E) {
            int d = dst[e];
            pk[k] = d >> PSH;
            rec[k] = ((unsigned int)(d & (PNODES - 1)) << 20) | (unsigned int)src[e];
            atomicAdd(&cnt[pk[k]], 1);
        } else pk[k] = -1;
    }
    __syncthreads();
    for (int i = tid; i < np; i += 256)
        if (cnt[i]) gb[i] = atomicAdd(&pcursor[i * CURPAD], cnt[i]);
    __syncthreads();
#pragma unroll
    for (int k = 0; k < 16; ++k) {
        if (pk[k] >= 0) {
            int off = atomicAdd(&loc[pk[k]], 1);
            barr[gb[pk[k]] + off] = rec[k];
        }
    }
}

// Block per partition (PNODES=256): LDS counting sort -> csr + row_start.
__global__ __launch_bounds__(256) void k_psort(const unsigned int* __restrict__ barr,
        const int* __restrict__ pstart, int* __restrict__ csr,
        int* __restrict__ row_start, int n, int np, int E) {
    __shared__ int hist[PNODES], curs[PNODES], tsum[256];
    int tid = threadIdx.x;
    int p = blockIdx.x;
    int e0 = pstart[p], e1 = pstart[p + 1];
    int node0 = p << PSH;
    hist[tid] = 0;
    __syncthreads();
    for (int t = e0 + tid; t < e1; t += 256)
        atomicAdd(&hist[barr[t] >> 20], 1);
    __syncthreads();
    int v = hist[tid];
    tsum[tid] = v; __syncthreads();
    for (int o = 1; o < 256; o <<= 1) {
        int u = (tid >= o) ? tsum[tid - o] : 0;
        __syncthreads(); tsum[tid] += u; __syncthreads();
    }
    int ex = tsum[tid] - v;
    curs[tid] = ex;
    int nd = node0 + tid;
    if (nd < n) row_start[nd] = e0 + ex;
    if (p == np - 1 && tid == 0) row_start[n] = E;
    __syncthreads();
    for (int t = e0 + tid; t < e1; t += 256) {
        unsigned int rec = barr[t];
        int pos = atomicAdd(&curs[rec >> 20], 1);
        csr[e0 + pos] = (int)(rec & 0xFFFFF);
    }
}

// ---- aggregation 0: bf16 gather on xb rows (128B), 4-deep batches -------
__global__ __launch_bounds__(256) void k_agg0(const u16* __restrict__ xb,
        const int* __restrict__ rs, const int* __restrict__ csr,
        u16* __restrict__ agg, int n) {
    int i = blockIdx.x * 4 + (threadIdx.x >> 6);
    if (i >= n) return;
    int lane = threadIdx.x & 63;
    int slot = lane >> 4, cp = lane & 15;   // xb row = 128B = 16 x uint2
    const unsigned int* x32 = (const unsigned int*)xb;
    int b = rs[i], e = rs[i + 1];
    float acc[4] = {0.f, 0.f, 0.f, 0.f};
    int t = b + slot;
    for (; t + 12 < e; t += 16) {
        int j0 = csr[t], j1 = csr[t + 4], j2 = csr[t + 8], j3 = csr[t + 12];
        uint2 w0 = *((const uint2*)(x32 + (long)j0 * 32) + cp);
        uint2 w1 = *((const uint2*)(x32 + (long)j1 * 32) + cp);
        uint2 w2 = *((const uint2*)(x32 + (long)j2 * 32) + cp);
        uint2 w3 = *((const uint2*)(x32 + (long)j3 * 32) + cp);
        acc[0] += lo16(w0.x) + lo16(w1.x); acc[1] += hi16(w0.x) + hi16(w1.x);
        acc[2] += lo16(w0.y) + lo16(w1.y); acc[3] += hi16(w0.y) + hi16(w1.y);
        acc[0] += lo16(w2.x) + lo16(w3.x); acc[1] += hi16(w2.x) + hi16(w3.x);
        acc[2] += lo16(w2.y) + lo16(w3.y); acc[3] += hi16(w2.y) + hi16(w3.y);
    }
    for (; t < e; t += 4) {
        int j0 = csr[t];
        uint2 w0 = *((const uint2*)(x32 + (long)j0 * 32) + cp);
        acc[0] += lo16(w0.x); acc[1] += hi16(w0.x);
        acc[2] += lo16(w0.y); acc[3] += hi16(w0.y);
    }
#pragma unroll
    for (int k = 0; k < 4; ++k) {
        acc[k] += __shfl_xor(acc[k], 16);
        acc[k] += __shfl_xor(acc[k], 32);
    }
    if (slot == 0) {
        uint2 o;
        o.x = (unsigned int)f2bf(acc[0]) | ((unsigned int)f2bf(acc[1]) << 16);
        o.y = (unsigned int)f2bf(acc[2]) | ((unsigned int)f2bf(acc[3]) << 16);
        *((uint2*)((unsigned int*)agg + (long)i * 32) + cp) = o;
    }
}

// ---- y0p = relu(bn0(y0)) materialized IN-PLACE (bf16), streaming --------
__global__ __launch_bounds__(256) void k_y0p(unsigned int* __restrict__ y0,
        const float* __restrict__ sc, const float* __restrict__ sh, long nq) {
    long idx = (long)blockIdx.x * 256 + threadIdx.x;
    int colq = threadIdx.x & 15;
    float s8[8], h8[8];
#pragma unroll
    for (int j = 0; j < 8; ++j) { s8[j] = sc[colq * 8 + j]; h8[j] = sh[colq * 8 + j]; }
    long stride = (long)gridDim.x * 256;
    uint4* p = (uint4*)y0;
    for (; idx < nq; idx += stride) {
        uint4 w = p[idx];
        unsigned int r[4] = {w.x, w.y, w.z, w.w};
        uint4 o;
        unsigned int* po = (unsigned int*)&o;
#pragma unroll
        for (int d = 0; d < 4; ++d) {
            float a = fmaxf(lo16(r[d]) * s8[2 * d]     + h8[2 * d],     0.f);
            float b = fmaxf(hi16(r[d]) * s8[2 * d + 1] + h8[2 * d + 1], 0.f);
            po[d] = (unsigned int)f2bf(a) | ((unsigned int)f2bf(b) << 16);
        }
        p[idx] = o;
    }
}

// ------- aggregation 1 (R14 form): pure bf16 gather, 4-deep batches ------
__global__ __launch_bounds__(256) void k_agg1(const u16* __restrict__ y0p,
        const int* __restrict__ rs, const int* __restrict__ csr,
        u16* __restrict__ agg, int n) {
    int i = blockIdx.x * 4 + (threadIdx.x >> 6);
    if (i >= n) return;
    int lane = threadIdx.x & 63;
    int slot = lane >> 4, cp = lane & 15;   // y0p row = 256B = 16 x uint4
    const unsigned int* y32 = (const unsigned int*)y0p;
    int b = rs[i], e = rs[i + 1];
    float acc[8] = {0.f, 0.f, 0.f, 0.f, 0.f, 0.f, 0.f, 0.f};
    int t = b + slot;
    for (; t + 12 < e; t += 16) {
        int j0 = csr[t], j1 = csr[t + 4], j2 = csr[t + 8], j3 = csr[t + 12];
        uint4 w0 = *((const uint4*)(y32 + (long)j0 * 64) + cp);
        uint4 w1 = *((const uint4*)(y32 + (long)j1 * 64) + cp);
        uint4 w2 = *((const uint4*)(y32 + (long)j2 * 64) + cp);
        uint4 w3 = *((const uint4*)(y32 + (long)j3 * 64) + cp);
        acc8(acc, w0); acc8(acc, w1); acc8(acc, w2); acc8(acc, w3);
    }
    for (; t < e; t += 4) {
        int j0 = csr[t];
        uint4 w0 = *((const uint4*)(y32 + (long)j0 * 64) + cp);
        acc8(acc, w0);
    }
#pragma unroll
    for (int k = 0; k < 8; ++k) {
        acc[k] += __shfl_xor(acc[k], 16);
        acc[k] += __shfl_xor(acc[k], 32);
    }
    if (slot == 0) {
        uint4 o;
        o.x = (unsigned int)f2bf(acc[0]) | ((unsigned int)f2bf(acc[1]) << 16);
        o.y = (unsigned int)f2bf(acc[2]) | ((unsigned int)f2bf(acc[3]) << 16);
        o.z = (unsigned int)f2bf(acc[4]) | ((unsigned int)f2bf(acc[5]) << 16);
        o.w = (unsigned int)f2bf(acc[6]) | ((unsigned int)f2bf(acc[7]) << 16);
        *((uint4*)((unsigned int*)agg + (long)i * 64) + cp) = o;
    }
}

// ------ GEMM0 (direct-global): y0 = [xb|agg0] @ [Wr0;Wn0]^T, stats --------
template<bool BF>
__device__ __forceinline__ void gemm0_impl(const u16* xb, const u16* agg,
                                           const void* Wr, const void* Wn,
                                           u16* y0, float* sumP, float* sqP,
                                           int n, int nch) {
    int tid = threadIdx.x;
    int wave = tid >> 6, lane = tid & 63, lr = lane & 15, q = lane >> 4;

    short8 wf[2][4];
#pragma unroll
    for (int i = 0; i < 2; ++i) {
        int c = (2 * wave + i) * 16 + lr;
#pragma unroll
        for (int ks = 0; ks < 4; ++ks) {
            const void* W = (ks < 2) ? Wr : Wn;
            wf[i][ks] = ld8<BF>(W, (long)c * CIN + (ks & 1) * 32 + q * 8);
        }
    }

    float st[2] = {0.f, 0.f}, sq[2] = {0.f, 0.f};
    for (int ch = blockIdx.x; ch < nch; ch += gridDim.x) {
        long chunk0 = (long)ch * 64;
#pragma unroll
        for (int t = 0; t < 4; ++t) {
            long rg = chunk0 + t * 16 + lr; if (rg > n - 1) rg = n - 1;
            short8 a[4];
#pragma unroll
            for (int ks = 0; ks < 2; ++ks)
                a[ks] = *(const short8*)(xb + rg * CIN + ks * 32 + q * 8);
#pragma unroll
            for (int ks = 0; ks < 2; ++ks)
                a[2 + ks] = *(const short8*)(agg + rg * CIN + ks * 32 + q * 8);
#pragma unroll
            for (int i = 0; i < 2; ++i) {
                f32x4 acc = {0.f, 0.f, 0.f, 0.f};
#pragma unroll
                for (int ks = 0; ks < 4; ++ks)
                    acc = __builtin_amdgcn_mfma_f32_16x16x32_bf16(a[ks], wf[i][ks], acc, 0, 0, 0);
                int c = (2 * wave + i) * 16 + lr;
#pragma unroll
                for (int r = 0; r < 4; ++r) {
                    long row = chunk0 + t * 16 + q * 4 + r;
                    if (row < n) {
                        y0[row * COUT + c] = f2bf(acc[r]);   // b0 cancels in BN
                        st[i] += acc[r]; sq[i] += acc[r] * acc[r];
                    }
                }
            }
        }
    }
#pragma unroll
    for (int i = 0; i < 2; ++i) {
        st[i] += __shfl_xor(st[i], 16); st[i] += __shfl_xor(st[i], 32);
        sq[i] += __shfl_xor(sq[i], 16); sq[i] += __shfl_xor(sq[i], 32);
    }
    if (q == 0) {
#pragma unroll
        for (int i = 0; i < 2; ++i) {
            int c = (2 * wave + i) * 16 + lr;
            atomicAdd(&sumP[c * SPAD], st[i]);
            atomicAdd(&sqP[c * SPAD], sq[i]);
        }
    }
}

__global__ __launch_bounds__(256) void k_gemm0(const int* __restrict__ flag,
        const u16* __restrict__ xb, const u16* __restrict__ agg,
        const void* Wr, const void* Wn,
        u16* __restrict__ y0, float* __restrict__ sumP, float* __restrict__ sqP,
        int n, int nch) {
    if (*flag) gemm0_impl<true >(xb, agg, Wr, Wn, y0, sumP, sqP, n, nch);
    else       gemm0_impl<false>(xb, agg, Wr, Wn, y0, sumP, sqP, n, nch);
}

// ------ GEMM1 (direct-global): y1 = [y0p|agg1] @ [Wr1;Wn1]^T --------------
template<bool BF>
__device__ __forceinline__ void gemm1_impl(const u16* y0p, const u16* agg,
                                           const void* Wr, const void* Wn,
                                           u16* y1, float* sumP, float* sqP,
                                           int n, int nch) {
    int tid = threadIdx.x;
    int wave = tid >> 6, lane = tid & 63, lr = lane & 15, q = lane >> 4;

    short8 wf[2][8];
#pragma unroll
    for (int i = 0; i < 2; ++i) {
        int c = (2 * wave + i) * 16 + lr;
#pragma unroll
        for (int ks = 0; ks < 8; ++ks) {
            const void* W = (ks < 4) ? Wr : Wn;
            wf[i][ks] = ld8<BF>(W, (long)c * COUT + (ks & 3) * 32 + q * 8);
        }
    }

    float st[2] = {0.f, 0.f}, sq[2] = {0.f, 0.f};
    for (int ch = blockIdx.x; ch < nch; ch += gridDim.x) {
        long chunk0 = (long)ch * 64;
#pragma unroll
        for (int t = 0; t < 4; ++t) {
            long rg = chunk0 + t * 16 + lr; if (rg > n - 1) rg = n - 1;
            short8 a[8];
#pragma unroll
            for (int ks = 0; ks < 4; ++ks)
                a[ks] = *(const short8*)(y0p + rg * COUT + ks * 32 + q * 8);
#pragma unroll
            for (int ks = 0; ks < 4; ++ks)
                a[4 + ks] = *(const short8*)(agg + rg * COUT + ks * 32 + q * 8);
#pragma unroll
            for (int i = 0; i < 2; ++i) {
                f32x4 acc = {0.f, 0.f, 0.f, 0.f};
#pragma unroll
                for (int ks = 0; ks < 8; ++ks)
                    acc = __builtin_amdgcn_mfma_f32_16x16x32_bf16(a[ks], wf[i][ks], acc, 0, 0, 0);
                int c = (2 * wave + i) * 16 + lr;
#pragma unroll
                for (int r = 0; r < 4; ++r) {
                    long row = chunk0 + t * 16 + q * 4 + r;
                    if (row < n) {
                        y1[row * COUT + c] = f2bf(acc[r]);   // b1 cancels in BN
                        st[i] += acc[r]; sq[i] += acc[r] * acc[r];
                    }
                }
            }
        }
    }
#pragma unroll
    for (int i = 0; i < 2; ++i) {
        st[i] += __shfl_xor(st[i], 16); st[i] += __shfl_xor(st[i], 32);
        sq[i] += __shfl_xor(sq[i], 16); sq[i] += __shfl_xor(sq[i], 32);
    }
    if (q == 0) {
#pragma unroll
        for (int i = 0; i < 2; ++i) {
            int c = (2 * wave + i) * 16 + lr;
            atomicAdd(&sumP[c * SPAD], st[i]);
            atomicAdd(&sqP[c * SPAD], sq[i]);
        }
    }
}

__global__ __launch_bounds__(256) void k_gemm1(const int* __restrict__ flag,
        const u16* __restrict__ y0p, const u16* __restrict__ agg,
        const void* Wr, const void* Wn,
        u16* y1_bf /*=d_out*/, u16* y1_ws,
        float* __restrict__ sumP, float* __restrict__ sqP, int n, int nch) {
    u16* y1 = *flag ? y1_bf : y1_ws;
    if (*flag) gemm1_impl<true >(y0p, agg, Wr, Wn, y1, sumP, sqP, n, nch);
    else       gemm1_impl<false>(y0p, agg, Wr, Wn, y1, sumP, sqP, n, nch);
}

// ---------------- BN finalize (reads line-padded stats) ----------------
__global__ void k_bnfin(const int* __restrict__ flag,
                        const float* __restrict__ sumP, const float* __restrict__ sqP,
                        const void* g, const void* be,
                        float* __restrict__ scale, float* __restrict__ shift, int n) {
    int c = threadIdx.x;
    bool bf = (*flag != 0);
    float inv = 1.f / (float)n;
    float mu = sumP[c * SPAD] * inv;
    float var = fmaxf(sqP[c * SPAD] * inv - mu * mu, 0.f);
    float gv = bf ? bf2f(((const u16*)g)[c]) : ((const float*)g)[c];
    float bv = bf ? bf2f(((const u16*)be)[c]) : ((const float*)be)[c];
    float sc = gv * rsqrtf(var + BN_EPS);
    scale[c] = sc;
    shift[c] = bv - mu * sc;
}

// -------- final: out = relu(bn1(y1) + xb@Wlin^T + blin) -------------------
// x-feed direct from xb; LDS stages only y1 (for transposed elementwise read).
template<bool BF>
__device__ __forceinline__ void final_impl(const u16* xb, const u16* y1,
                                           const void* Wlin, const void* blin,
                                           const float* sc, const float* sh,
                                           void* out, int n, int nch, u16* lds) {
    const int ST = 130;
    int tid = threadIdx.x;
    int wave = tid >> 6, lane = tid & 63, lr = lane & 15, q = lane >> 4;

    short8 wf[2][2];
    float blc[2], scc[2], shc[2];
#pragma unroll
    for (int i = 0; i < 2; ++i) {
        int c = (2 * wave + i) * 16 + lr;
#pragma unroll
        for (int ks = 0; ks < 2; ++ks)
            wf[i][ks] = ld8<BF>(Wlin, (long)c * CIN + ks * 32 + q * 8);
        blc[i] = ldf<BF>(blin, c);
        scc[i] = sc[c]; shc[i] = sh[c];
    }

    const int rowy = tid >> 4, wy = tid & 15;
    short8 ry[4];

    auto regload = [&](long chunk0) {
#pragma unroll
        for (int i = 0; i < 4; ++i) {
            long rg = chunk0 + rowy + i * 16; if (rg > n - 1) rg = n - 1;
            ry[i] = *(const short8*)(y1 + rg * COUT + wy * 8);
        }
    };

    int ch = blockIdx.x;
    if (ch < nch) regload((long)ch * 64);
    for (; ch < nch; ch += gridDim.x) {
        long chunk0 = (long)ch * 64;
        __syncthreads();
#pragma unroll
        for (int i = 0; i < 4; ++i)
            *(short8*)(lds + (rowy + i * 16) * ST + wy * 8) = ry[i];
        __syncthreads();
        long nxt = (long)ch + gridDim.x;
        if (nxt < nch) regload(nxt * 64);

#pragma unroll
        for (int t = 0; t < 4; ++t) {
            long rg = chunk0 + t * 16 + lr; if (rg > n - 1) rg = n - 1;
            short8 a[2];
#pragma unroll
            for (int ks = 0; ks < 2; ++ks)
                a[ks] = *(const short8*)(xb + rg * CIN + ks * 32 + q * 8);
#pragma unroll
            for (int i = 0; i < 2; ++i) {
                f32x4 acc = {0.f, 0.f, 0.f, 0.f};
                acc = __builtin_amdgcn_mfma_f32_16x16x32_bf16(a[0], wf[i][0], acc, 0, 0, 0);
                acc = __builtin_amdgcn_mfma_f32_16x16x32_bf16(a[1], wf[i][1], acc, 0, 0, 0);
                int c = (2 * wave + i) * 16 + lr;
#pragma unroll
                for (int r = 0; r < 4; ++r) {
                    long row = chunk0 + t * 16 + q * 4 + r;
                    if (row < n) {
                        float yv = bf2f(lds[(t * 16 + q * 4 + r) * ST + c]);
                        float v = acc[r] + blc[i] + yv * scc[i] + shc[i];
                        v = fmaxf(v, 0.f);
                        if (BF) ((u16*)out)[row * COUT + c] = f2bf(v);
                        else    ((float*)out)[row * COUT + c] = v;
                    }
                }
            }
        }
    }
}

__global__ __launch_bounds__(256) void k_final(const int* __restrict__ flag,
        const u16* __restrict__ xb, const void* Wlin, const void* blin,
        const u16* y1_bf /*=d_out*/, const u16* y1_ws,
        const float* __restrict__ sc, const float* __restrict__ sh,
        void* out, int n, int nch) {
    __shared__ u16 lds[64 * 130];
    const u16* y1 = *flag ? y1_bf : y1_ws;
    if (*flag) final_impl<true >(xb, y1, Wlin, blin, sc, sh, out, n, nch, lds);
    else       final_impl<false>(xb, y1, Wlin, blin, sc, sh, out, n, nch, lds);
}

extern "C" void kernel_launch(void* const* d_in, const int* in_sizes, int n_in,
                              void* d_out, int out_size, void* d_ws, size_t ws_size,
                              hipStream_t stream) {
    (void)n_in; (void)out_size; (void)ws_size;
    const void* x    = d_in[0];
    const int*  ei   = (const int*)d_in[1];
    const void* Wr0  = d_in[2];
    const void* Wn0  = d_in[3];
    /* b0 dropped: BN-invariant */
    const void* g0   = d_in[5];
    const void* be0  = d_in[6];
    const void* Wr1  = d_in[7];
    const void* Wn1  = d_in[8];
    /* b1 dropped */
    const void* g1   = d_in[10];
    const void* be1  = d_in[11];
    const void* Wlin = d_in[12];
    const void* blin = d_in[13];

    const int N = in_sizes[0] / CIN;
    const int E = in_sizes[1] / 2;
    const int* src = ei;
    const int* dst = ei + E;
    const int NP = (N + PNODES - 1) >> PSH;

    // ---- workspace carve (256B aligned); f32-only region LAST ----
    char* base = (char*)d_ws;
    size_t off = 0;
    auto carve = [&](size_t bytes) -> void* {
        void* p = base + off;
        off = (off + bytes + 255) & ~(size_t)255;
        return p;
    };
    int*   flag      = (int*)carve(256);
    int*   pcount    = (int*)carve(MAXP * PCPAD * sizeof(int));
    int*   pstart    = (int*)carve((MAXP + 1) * sizeof(int));
    int*   pcursor   = (int*)carve(MAXP * CURPAD * sizeof(int));
    float* statsP    = (float*)carve(4 * 128 * SPAD * sizeof(float));
    float* scsh      = (float*)carve(512 * sizeof(float));
    int*   row_start = (int*)carve((size_t)(N + 1) * sizeof(int));
    unsigned int* barr = (unsigned int*)carve((size_t)E * sizeof(int));
    int*   csr       = (int*)carve((size_t)E * sizeof(int));
    u16*   xb        = (u16*)carve((size_t)N * CIN * sizeof(u16));
    u16*   aggu      = (u16*)carve((size_t)N * COUT * sizeof(u16));
    u16*   y0        = (u16*)carve((size_t)N * COUT * sizeof(u16));
    u16*   y1_ws     = (u16*)carve((size_t)N * COUT * sizeof(u16));

    float* sum0P = statsP;
    float* sq0P  = statsP + 128 * SPAD;
    float* sum1P = statsP + 256 * SPAD;
    float* sq1P  = statsP + 384 * SPAD;

    hipMemsetAsync(pcount, 0, MAXP * PCPAD * sizeof(int), stream);
    hipMemsetAsync(statsP, 0, 4 * 128 * SPAD * sizeof(float), stream);

    const int nwb = (N + 3) / 4;        // wave-per-node agg blocks
    const int nch = (N + 63) / 64;
    const int ntl = (E + 4095) / 4096;
    const int G   = nch < 1024 ? nch : 1024;
    const long nq = (long)N * 16;       // y0 uint4-quads
    const long n8 = (long)N * CIN / 8;  // xb 8-elem groups
    int g2 = (int)((nq + 255) / 256); if (g2 > 2048) g2 = 2048;
    int g3 = (int)((n8 + 255) / 256); if (g3 > 2048) g3 = 2048;

    k_detect<<<1, 64, 0, stream>>>((const unsigned int*)x, flag);
    k_xbf<<<g3, 256, 0, stream>>>(flag, x, xb, n8);

    k_phist<<<256, 256, 0, stream>>>(dst, pcount, E, NP);
    k_pscan<<<1, MAXP, 0, stream>>>(pcount, pstart, pcursor, NP, E);
    k_pfill<<<ntl, 256, 0, stream>>>(src, dst, pcursor, barr, E, NP);
    k_psort<<<NP, 256, 0, stream>>>(barr, pstart, csr, row_start, N, NP, E);

    k_agg0 <<<nwb, 256, 0, stream>>>(xb, row_start, csr, aggu, N);
    k_gemm0<<<G, 256, 0, stream>>>(flag, xb, aggu, Wr0, Wn0, y0,
                                   sum0P, sq0P, N, nch);
    k_bnfin<<<1, 128, 0, stream>>>(flag, sum0P, sq0P, g0, be0,
                                   scsh, scsh + 128, N);

    k_y0p<<<g2, 256, 0, stream>>>((unsigned int*)y0, scsh, scsh + 128, nq);

    k_agg1 <<<nwb, 256, 0, stream>>>(y0, row_start, csr, aggu, N);
    k_gemm1<<<G, 256, 0, stream>>>(flag, y0, aggu, Wr1, Wn1,
                                   (u16*)d_out, y1_ws, sum1P, sq1P, N, nch);
    k_bnfin<<<1, 128, 0, stream>>>(flag, sum1P, sq1P, g1, be1,
                                   scsh + 256, scsh + 384, N);

    k_final<<<G, 256, 0, stream>>>(flag, xb, Wlin, blin,
                                   (const u16*)d_out, y1_ws,
                                   scsh + 256, scsh + 384, d_out, N, nch);
}